// Round 11
// baseline (366.934 us; speedup 1.0000x reference)
//
#include <hip/hip_runtime.h>
#include <hip/hip_bf16.h>

typedef _Float16 f16;
typedef __attribute__((ext_vector_type(8))) _Float16 half8;
typedef __attribute__((ext_vector_type(4))) _Float16 half4;
typedef __attribute__((ext_vector_type(4))) float f32x4;

#define AS1 __attribute__((address_space(1)))
#define AS3 __attribute__((address_space(3)))

constexpr int CH  = 512;    // channels
constexpr int NSP = 4096;   // 64*64 spatial
constexpr int NB  = 4;      // batch

#define VM8  asm volatile("s_waitcnt vmcnt(8)"  ::: "memory")
#define VM6  asm volatile("s_waitcnt vmcnt(6)"  ::: "memory")
#define VM4  asm volatile("s_waitcnt vmcnt(4)"  ::: "memory")
#define VM2  asm volatile("s_waitcnt vmcnt(2)"  ::: "memory")
#define VM0  asm volatile("s_waitcnt vmcnt(0)"  ::: "memory")
#define BARS do { __builtin_amdgcn_s_barrier(); asm volatile("" ::: "memory"); } while (0)
#define SP1  __builtin_amdgcn_s_setprio(1)
#define SP0  __builtin_amdgcn_s_setprio(0)

__device__ __forceinline__ void gload_lds16(const void* g, void* l) {
    __builtin_amdgcn_global_load_lds((const AS1 void*)g, (AS3 void*)l, 16, 0, 0);
}

// ---------------------------------------------------------------- transpose f32[c][n] -> f16[n][c] + fused stats
__global__ void transpose_f16_kernel(const float* __restrict__ content, const float* __restrict__ style,
                                     f16* __restrict__ content_t, f16* __restrict__ style_t,
                                     float* __restrict__ raw)
{
    int b = blockIdx.z & 3, is_style = blockIdx.z >> 2;
    const float* src = (is_style ? style : content) + (size_t)b * CH * NSP;
    f16* dst = (is_style ? style_t : content_t) + (size_t)b * NSP * CH;
    int c0 = blockIdx.y * 64, n0 = blockIdx.x * 64;
    __shared__ f16 tile[64][72];
    int t = threadIdx.x;
    #pragma unroll
    for (int i = 0; i < 4; i++) {
        int idx = t + i*256;
        int cr = idx >> 4, n4 = (idx & 15) * 4;
        float4 v = *(const float4*)(src + (size_t)(c0+cr)*NSP + n0 + n4);
        tile[cr][n4+0] = (f16)v.x; tile[cr][n4+1] = (f16)v.y;
        tile[cr][n4+2] = (f16)v.z; tile[cr][n4+3] = (f16)v.w;
    }
    __syncthreads();
    {
        int row = t >> 2, seg = (t & 3) * 16;
        float s1 = 0.f, s2 = 0.f;
        #pragma unroll
        for (int j = 0; j < 16; j++) {
            float x = (float)tile[row][seg + j];
            s1 += x; s2 += x * x;
        }
        s1 += __shfl_down(s1, 2, 4); s1 += __shfl_down(s1, 1, 4);
        s2 += __shfl_down(s2, 2, 4); s2 += __shfl_down(s2, 1, 4);
        if ((t & 3) == 0) {
            int si = is_style * 2 * NB * CH + b * CH + c0 + row;
            atomicAdd(&raw[si], s1);
            atomicAdd(&raw[si + NB * CH], s2);
        }
    }
    int nr = t >> 2, seg = (t & 3) * 16;
    __align__(16) f16 out_v[16];
    #pragma unroll
    for (int j = 0; j < 16; j++) out_v[j] = tile[seg + j][nr];
    f16* dp = dst + (size_t)(n0+nr)*CH + c0 + seg;
    *(int4*)dp = ((int4*)out_v)[0];
    *(int4*)(dp + 8) = ((int4*)out_v)[1];
}

// ---------------------------------------------------------------- effective weights (from raw sums)
__global__ void effw_kernel(const float* __restrict__ fw, const float* __restrict__ fb,
                            const float* __restrict__ gw, const float* __restrict__ gb,
                            const float* __restrict__ hw, const float* __restrict__ ow,
                            const float* __restrict__ raw,
                            f16* __restrict__ fw_e, float* __restrict__ fb_e,
                            f16* __restrict__ gw_e, float* __restrict__ gb_e,
                            f16* __restrict__ hw_h, f16* __restrict__ ow_h)
{
    int o = blockIdx.x, b = blockIdx.y, mode = blockIdx.z, t = threadIdx.x;
    if (mode >= 2) {
        if (b != 0) return;
        const float* srcw = (mode == 2) ? hw : ow;
        f16* dstw = (mode == 2) ? hw_h : ow_h;
        for (int c = t; c < CH; c += 128) dstw[o*CH + c] = (f16)srcw[o*CH + c];
        return;
    }
    const float* w  = mode ? gw : fw;
    const float* rw = raw + (mode ? 2*NB*CH : 0);
    f16* we = mode ? gw_e : fw_e;
    float part = 0.f;
    for (int c = t; c < CH; c += 128) {
        float s1 = rw[b*CH + c], s2 = rw[NB*CH + b*CH + c];
        float mn = s1 * (1.f/NSP);
        float var = (s2 - (float)NSP*mn*mn) * (1.f/(NSP-1));
        float is = rsqrtf(var + 1e-5f);
        float wv = w[o*CH + c];
        we[((size_t)b*CH + o)*CH + c] = (f16)(wv * is);
        part += wv * mn * is;
    }
    #pragma unroll
    for (int off = 32; off; off >>= 1) part += __shfl_down(part, off);
    __shared__ float rr[2];
    if ((t & 63) == 0) rr[t >> 6] = part;
    __syncthreads();
    if (t == 0) (mode ? gb_e : fb_e)[b*CH + o] = (mode ? gb : fb)[o] - (rr[0] + rr[1]);
}

// ---------------------------------------------------------------- fused F/G/H conv GEMM (K=512), m97-style
__global__ __launch_bounds__(256)
void conv3_kernel(const f16* __restrict__ fw_e, const float* __restrict__ fb_e,
                  const f16* __restrict__ gw_e, const float* __restrict__ gb_e,
                  const f16* __restrict__ hw_h, const float* __restrict__ h_b,
                  const f16* __restrict__ content_t, const f16* __restrict__ style_t,
                  f16* __restrict__ F_t, f16* __restrict__ G_t, f16* __restrict__ H_)
{
    const int T = gridDim.x;   // 1536
    const int bid = blockIdx.x;
    const int tile = (bid & 7) * (T >> 3) + (bid >> 3);
    const int zz = tile >> 7, rem = tile & 127;
    const int mt = rem >> 5, nt = rem & 31;
    const int kind = zz >> 2, b = zz & 3;

    const f16* W; const float* bias; const f16* Xt; f16* Y;
    if (kind == 0)      { W = fw_e + (size_t)b*CH*CH; bias = fb_e + b*CH; Xt = content_t + (size_t)b*NSP*CH; Y = F_t + (size_t)b*NSP*CH; }
    else if (kind == 1) { W = gw_e + (size_t)b*CH*CH; bias = gb_e + b*CH; Xt = style_t + (size_t)b*NSP*CH; Y = G_t + (size_t)b*NSP*CH; }
    else                { W = hw_h;                    bias = h_b;         Xt = style_t + (size_t)b*NSP*CH; Y = H_ + (size_t)b*CH*NSP; }

    const int m0 = mt * 128, n0 = nt * 128;
    const int t = threadIdx.x, wave = t >> 6, lane = t & 63;
    const int l15 = lane & 15, l4 = lane >> 4;
    const int wm = (wave >> 1) * 64, wn = (wave & 1) * 64;

    __shared__ __align__(16) f16 Al[8192];
    __shared__ __align__(16) f16 Bl[8192];

    f32x4 acc[4][4] = {};

    for (int ks = 0; ks < CH/64; ks++) {
        const int kk = ks * 64;
        #pragma unroll
        for (int j = 0; j < 4; j++) {
            int L  = ((wave*4 + j)*64 + lane) * 16;
            int SL = L ^ (((L >> 7) & 7) << 4);
            int row = SL >> 7, seg = (SL & 127) >> 1;
            gload_lds16(W  + (size_t)(m0 + row)*CH + kk + seg, &Al[L >> 1]);
            gload_lds16(Xt + (size_t)(n0 + row)*CH + kk + seg, &Bl[L >> 1]);
        }
        VM0; BARS;
        #pragma unroll
        for (int kb = 0; kb < 2; kb++) {
            half8 a[4], bb[4];
            #pragma unroll
            for (int i = 0; i < 4; i++) {
                int ab = (wm + i*16 + l15)*128 + kb*64 + l4*16;
                ab ^= ((ab >> 7) & 7) << 4;
                a[i] = *(const half8*)&Al[ab >> 1];
                int bby = (wn + i*16 + l15)*128 + kb*64 + l4*16;
                bby ^= ((bby >> 7) & 7) << 4;
                bb[i] = *(const half8*)&Bl[bby >> 1];
            }
            #pragma unroll
            for (int i = 0; i < 4; i++)
                #pragma unroll
                for (int jj = 0; jj < 4; jj++)
                    acc[i][jj] = __builtin_amdgcn_mfma_f32_16x16x32_f16(a[i], bb[jj], acc[i][jj], 0, 0, 0);
        }
        BARS;
    }

    #pragma unroll
    for (int i = 0; i < 4; i++) {
        const int ob = m0 + wm + i*16 + l4*4;
        f32x4 bv = *(const f32x4*)(bias + ob);
        #pragma unroll
        for (int jj = 0; jj < 4; jj++) {
            const int n = n0 + wn + jj*16 + l15;
            f32x4 v = acc[i][jj];
            v[0] += bv[0]; v[1] += bv[1]; v[2] += bv[2]; v[3] += bv[3];
            if (kind < 2) {
                half4 pk; pk[0]=(f16)v[0]; pk[1]=(f16)v[1]; pk[2]=(f16)v[2]; pk[3]=(f16)v[3];
                *(half4*)(Y + (size_t)n * CH + ob) = pk;
            } else {
                #pragma unroll
                for (int r = 0; r < 4; r++) Y[(size_t)(ob + r) * NSP + n] = (f16)v[r];
            }
        }
    }
}

// ---------------------------------------------------------------- 128x128 GEMM (out conv), proven R3
template<int MODE>   // 2: f32 Y[ob][n]
__global__ __launch_bounds__(256)
void gemm_kernel(const f16* __restrict__ W, long wstrideb,
                 const f16* __restrict__ Xt, long xstrideb,
                 const float* __restrict__ bias, long bstrideb,
                 void* __restrict__ Y, long ystrideb,
                 int K, long ostride)
{
    const int z = blockIdx.z;
    W    += (size_t)z * wstrideb;
    Xt   += (size_t)z * xstrideb;
    bias += (size_t)z * bstrideb;
    const int m0 = blockIdx.y * 128, n0 = blockIdx.x * 128;
    const int t = threadIdx.x, wave = t >> 6, lane = t & 63;
    const int l15 = lane & 15, l4 = lane >> 4;
    const int wm = (wave >> 1) * 64, wn = (wave & 1) * 64;

    __shared__ __align__(16) f16 Al[2][8192];
    __shared__ __align__(16) f16 Bl[2][8192];

    f32x4 acc[4][4] = {};

    auto stage = [&](int bufi, int kk) {
        #pragma unroll
        for (int j = 0; j < 4; j++) {
            int L  = ((wave*4 + j)*64 + lane) * 16;
            int SL = L ^ (((L >> 7) & 7) << 4);
            int row = SL >> 7, seg = (SL & 127) >> 1;
            gload_lds16(W  + (size_t)(m0 + row)*K + kk + seg, &Al[bufi][L >> 1]);
            gload_lds16(Xt + (size_t)(n0 + row)*K + kk + seg, &Bl[bufi][L >> 1]);
        }
    };

    const int nks = K >> 6;
    stage(0, 0);
    for (int ks = 0; ks < nks; ks++) {
        int bufi = ks & 1;
        if (ks < nks-1) { stage(bufi ^ 1, (ks + 1) * 64); VM8; }
        else            { VM0; }
        BARS;
        #pragma unroll
        for (int kb = 0; kb < 2; kb++) {
            half8 a[4], bb[4];
            #pragma unroll
            for (int i = 0; i < 4; i++) {
                int ab = (wm + i*16 + l15)*128 + kb*64 + l4*16;
                ab ^= ((ab >> 7) & 7) << 4;
                a[i] = *(const half8*)&Al[bufi][ab >> 1];
                int bby = (wn + i*16 + l15)*128 + kb*64 + l4*16;
                bby ^= ((bby >> 7) & 7) << 4;
                bb[i] = *(const half8*)&Bl[bufi][bby >> 1];
            }
            #pragma unroll
            for (int i = 0; i < 4; i++)
                #pragma unroll
                for (int jj = 0; jj < 4; jj++)
                    acc[i][jj] = __builtin_amdgcn_mfma_f32_16x16x32_f16(a[i], bb[jj], acc[i][jj], 0, 0, 0);
        }
        BARS;
    }

    #pragma unroll
    for (int i = 0; i < 4; i++) {
        const int ob = m0 + wm + i*16 + l4*4;
        f32x4 bv = *(const f32x4*)(bias + ob);
        #pragma unroll
        for (int jj = 0; jj < 4; jj++) {
            const int n = n0 + wn + jj*16 + l15;
            f32x4 v = acc[i][jj];
            v[0] += bv[0]; v[1] += bv[1]; v[2] += bv[2]; v[3] += bv[3];
            float* Yf = (float*)Y + (size_t)z * ystrideb;
            #pragma unroll
            for (int r = 0; r < 4; r++) Yf[(size_t)(ob + r) * ostride + n] = v[r];
        }
    }
}

// ---------------------------------------------------------------- attention GEMM fallback (m97-style)
template<int TPB, int NCT>
__global__ __launch_bounds__(256)
void gemm_att_kernel(const f16* __restrict__ W, long wstrideb,
                     const f16* __restrict__ Xt, long xstrideb,
                     f16* __restrict__ Y, long ystrideb,
                     int K, long ostride)
{
    const int T = gridDim.x;
    const int bid = blockIdx.x;
    const int tile = (bid & 7) * (T >> 3) + (bid >> 3);
    const int z = tile / TPB, rem = tile - z * TPB;
    const int mt = rem / NCT, nt = rem - mt * NCT;
    W  += (size_t)z * wstrideb;
    Xt += (size_t)z * xstrideb;
    f16* Yb = Y + (size_t)z * ystrideb;
    const int m0 = mt * 128, n0 = nt * 128;

    const int t = threadIdx.x, wave = t >> 6, lane = t & 63;
    const int l15 = lane & 15, l4 = lane >> 4;
    const int wm = (wave >> 1) * 64, wn = (wave & 1) * 64;

    __shared__ __align__(16) f16 Al[8192];
    __shared__ __align__(16) f16 Bl[8192];

    f32x4 acc[4][4] = {};

    const int nks = K >> 6;
    for (int ks = 0; ks < nks; ks++) {
        const int kk = ks * 64;
        #pragma unroll
        for (int j = 0; j < 4; j++) {
            int L  = ((wave*4 + j)*64 + lane) * 16;
            int SL = L ^ (((L >> 7) & 7) << 4);
            int row = SL >> 7, seg = (SL & 127) >> 1;
            gload_lds16(W  + (size_t)(m0 + row)*K + kk + seg, &Al[L >> 1]);
            gload_lds16(Xt + (size_t)(n0 + row)*K + kk + seg, &Bl[L >> 1]);
        }
        VM0; BARS;
        #pragma unroll
        for (int kb = 0; kb < 2; kb++) {
            half8 a[4], bb[4];
            #pragma unroll
            for (int i = 0; i < 4; i++) {
                int ab = (wm + i*16 + l15)*128 + kb*64 + l4*16;
                ab ^= ((ab >> 7) & 7) << 4;
                a[i] = *(const half8*)&Al[ab >> 1];
                int bby = (wn + i*16 + l15)*128 + kb*64 + l4*16;
                bby ^= ((bby >> 7) & 7) << 4;
                bb[i] = *(const half8*)&Bl[bby >> 1];
            }
            #pragma unroll
            for (int i = 0; i < 4; i++)
                #pragma unroll
                for (int jj = 0; jj < 4; jj++)
                    acc[i][jj] = __builtin_amdgcn_mfma_f32_16x16x32_f16(a[i], bb[jj], acc[i][jj], 0, 0, 0);
        }
        BARS;
    }

    #pragma unroll
    for (int i = 0; i < 4; i++) {
        const int ob = m0 + wm + i*16 + l4*4;
        #pragma unroll
        for (int jj = 0; jj < 4; jj++) {
            const int ncol = n0 + wn + jj*16 + l15;
            #pragma unroll
            for (int r = 0; r < 4; r++)
                Yb[(size_t)(ob + r) * ostride + ncol] = (f16)acc[i][jj][r];
        }
    }
}

// ---------------------------------------------------------------- 128x256 single-buffer GEMM (S): 256 thr,
// 4 waves each 128x64; LDS 48KB -> 2 blocks/CU (cross-block TLP hides stage drain + barriers).
// m97 2-barrier loop; transposed half4 store Yt[ncol][ob] (coalesced, 4x fewer store instrs).
template<int TPB, int NCT, int SPLITK>
__global__ __launch_bounds__(256)
void gemm_att2_kernel(const f16* __restrict__ W, long wstrideb,
                      const f16* __restrict__ Xt, long xstrideb,
                      f16* __restrict__ Y0, f16* __restrict__ Y1, long ystrideb,
                      int K, int kstride, long ostride)
{
    const int T = gridDim.x;
    const int bid = blockIdx.x;
    const int tile = (bid & 7) * (T >> 3) + (bid >> 3);
    int rem = tile, sp = 0;
    if constexpr (SPLITK == 2) { sp = tile / (NB * TPB); rem = tile - sp * NB * TPB; }
    const int z = rem / TPB; rem -= z * TPB;
    const int mt = rem / NCT, nt = rem - mt * NCT;
    const f16* Wb = W  + (size_t)z * wstrideb + (size_t)sp * K;
    const f16* Xb = Xt + (size_t)z * xstrideb + (size_t)sp * K;
    f16* Yb = ((SPLITK == 2 && sp) ? Y1 : Y0) + (size_t)z * ystrideb;
    const int m0 = mt * 128, n0 = nt * 256;

    const int t = threadIdx.x, wave = t >> 6, lane = t & 63;
    const int l15 = lane & 15, l4 = lane >> 4;
    const int wn = wave * 64;                    // per-wave n-slice

    __shared__ __align__(16) f16 As[8192];       // [128 rows][64 k], swizzled (16KB)
    __shared__ __align__(16) f16 Bs[16384];      // [256 rows][64 k], swizzled (32KB)

    f32x4 acc[8][4] = {};

    auto ldA = [&](int i, int kb) {
        int L = (i*16 + l15)*128 + kb*64 + l4*16;
        L ^= ((L >> 7) & 7) << 4;
        return *(const half8*)&As[L >> 1];
    };
    auto ldB = [&](int j, int kb) {
        int L = (wn + j*16 + l15)*128 + kb*64 + l4*16;
        L ^= ((L >> 7) & 7) << 4;
        return *(const half8*)&Bs[L >> 1];
    };

    const int nks = K >> 6;
    for (int ks = 0; ks < nks; ks++) {
        const int kk = ks * 64;
        #pragma unroll
        for (int q = 0; q < 4; q++) {            // A: 16KB = 4 x (256 thr x 16B)
            int L  = (q*256 + t) * 16;
            int SL = L ^ (((L >> 7) & 7) << 4);
            gload_lds16(Wb + (size_t)(m0 + (SL >> 7)) * kstride + kk + ((SL & 127) >> 1), &As[L >> 1]);
        }
        #pragma unroll
        for (int q = 0; q < 8; q++) {            // B: 32KB = 8 x (256 thr x 16B)
            int L  = (q*256 + t) * 16;
            int SL = L ^ (((L >> 7) & 7) << 4);
            gload_lds16(Xb + (size_t)(n0 + (SL >> 7)) * kstride + kk + ((SL & 127) >> 1), &Bs[L >> 1]);
        }
        VM0; BARS;

        half8 a[4][2], b[4][2];
        #pragma unroll
        for (int i = 0; i < 4; i++) { a[i][0] = ldA(i, 0); a[i][1] = ldA(i, 1); }
        #pragma unroll
        for (int j = 0; j < 4; j++) { b[j][0] = ldB(j, 0); b[j][1] = ldB(j, 1); }
        SP1;
        #pragma unroll
        for (int i = 0; i < 4; i++)
            #pragma unroll
            for (int j = 0; j < 4; j++)
                #pragma unroll
                for (int kb = 0; kb < 2; kb++)
                    acc[i][j] = __builtin_amdgcn_mfma_f32_16x16x32_f16(a[i][kb], b[j][kb], acc[i][j], 0, 0, 0);
        SP0;
        #pragma unroll
        for (int i = 0; i < 4; i++) { a[i][0] = ldA(4+i, 0); a[i][1] = ldA(4+i, 1); }
        SP1;
        #pragma unroll
        for (int i = 0; i < 4; i++)
            #pragma unroll
            for (int j = 0; j < 4; j++)
                #pragma unroll
                for (int kb = 0; kb < 2; kb++)
                    acc[4+i][j] = __builtin_amdgcn_mfma_f32_16x16x32_f16(a[i][kb], b[j][kb], acc[4+i][j], 0, 0, 0);
        SP0; BARS;
    }

    // transposed store: Yt[ncol][ob], per (i,j) one half4 (rows ob..ob+3)
    #pragma unroll
    for (int i = 0; i < 8; i++) {
        const int ob = m0 + i*16 + l4*4;
        #pragma unroll
        for (int j = 0; j < 4; j++) {
            const int ncol = n0 + wn + j*16 + l15;
            f32x4 v = acc[i][j];
            half4 pk; pk[0]=(f16)v[0]; pk[1]=(f16)v[1]; pk[2]=(f16)v[2]; pk[3]=(f16)v[3];
            *(half4*)(Yb + (size_t)ncol * ostride + ob) = pk;
        }
    }
}

// ---------------------------------------------------------------- 256x256 8-phase GEMM (PV, proven R10)
template<int TPB, int NCT, int SPLITK>
__global__ __launch_bounds__(512)
void gemm256_kernel(const f16* __restrict__ W, long wstrideb,
                    const f16* __restrict__ Xt, long xstrideb,
                    f16* __restrict__ Y0, f16* __restrict__ Y1, long ystrideb,
                    int K, int kstride, long ostride)
{
    const int T = gridDim.x;
    const int bid = blockIdx.x;
    const int tile = (bid & 7) * (T >> 3) + (bid >> 3);
    int rem = tile, sp = 0;
    if constexpr (SPLITK == 2) { sp = tile / (NB * TPB); rem = tile - sp * NB * TPB; }
    const int z = rem / TPB; rem -= z * TPB;
    const int mt = rem / NCT, nt = rem - mt * NCT;
    const f16* Wb = W  + (size_t)z * wstrideb + (size_t)sp * K;
    const f16* Xb = Xt + (size_t)z * xstrideb + (size_t)sp * K;
    f16* Yb = ((SPLITK == 2 && sp) ? Y1 : Y0) + (size_t)z * ystrideb;
    const int m0 = mt * 256, n0 = nt * 256;

    const int t = threadIdx.x, lane = t & 63, wave = t >> 6;
    const int l15 = lane & 15, l4 = lane >> 4;
    const int wr = wave >> 2, wc = wave & 3;

    __shared__ __align__(16) f16 As[2][16384];
    __shared__ __align__(16) f16 Bs[2][16384];

    f32x4 acc[8][4] = {};

    auto stA = [&](int nbuf, int kk, int half, int q) {
        int L  = half*16384 + q*8192 + t*16;
        int SL = L ^ (((L >> 7) & 7) << 4);
        gload_lds16(Wb + (size_t)(m0 + (SL >> 7)) * kstride + kk + ((SL & 127) >> 1), &As[nbuf][L >> 1]);
    };
    auto stB = [&](int nbuf, int kk, int half, int q) {
        int L  = half*16384 + q*8192 + t*16;
        int SL = L ^ (((L >> 7) & 7) << 4);
        gload_lds16(Xb + (size_t)(n0 + (SL >> 7)) * kstride + kk + ((SL & 127) >> 1), &Bs[nbuf][L >> 1]);
    };
    auto ldA = [&](int buf, int i, int kb) {
        int L = (((i&3)*16) + wr*64 + ((i>>2)*128) + l15)*128 + kb*64 + l4*16;
        L ^= ((L >> 7) & 7) << 4;
        return *(const half8*)&As[buf][L >> 1];
    };
    auto ldB = [&](int buf, int j, int kb) {
        int L = (((j&1)*16) + wc*32 + ((j>>1)*128) + l15)*128 + kb*64 + l4*16;
        L ^= ((L >> 7) & 7) << 4;
        return *(const half8*)&Bs[buf][L >> 1];
    };

    const int nks = K >> 6;
    stA(0,0,0,0); stA(0,0,0,1);
    stB(0,0,0,0); stB(0,0,0,1);
    stB(0,0,1,0); stB(0,0,1,1);
    stA(0,0,1,0); stA(0,0,1,1);
    VM4;
    if (nks > 1) {
        stA(1,64,0,0); stA(1,64,0,1);
        stB(1,64,0,0); stB(1,64,0,1);
        stB(1,64,1,0); stB(1,64,1,1);
        VM6;
    } else { VM0; }
    BARS;

    half8 a[4][2], b01[2][2], b23[2][2];

    for (int kt = 0; kt < nks; kt++) {
        const int buf = kt & 1;
        const int kk1 = (kt+1) << 6, kk2 = (kt+2) << 6;
        const bool s1 = (kt+1 < nks), s2 = (kt+2 < nks);

        #pragma unroll
        for (int i = 0; i < 4; i++) { a[i][0] = ldA(buf, i, 0); a[i][1] = ldA(buf, i, 1); }
        #pragma unroll
        for (int j = 0; j < 2; j++) { b01[j][0] = ldB(buf, j, 0); b01[j][1] = ldB(buf, j, 1); }
        if (s1) { stA(buf^1, kk1, 1, 0); stA(buf^1, kk1, 1, 1); }
        else    { VM2; }
        BARS; SP1;
        #pragma unroll
        for (int i = 0; i < 4; i++)
            #pragma unroll
            for (int j = 0; j < 2; j++)
                #pragma unroll
                for (int kb = 0; kb < 2; kb++)
                    acc[i][j] = __builtin_amdgcn_mfma_f32_16x16x32_f16(a[i][kb], b01[j][kb], acc[i][j], 0, 0, 0);
        SP0; BARS;

        #pragma unroll
        for (int j = 0; j < 2; j++) { b23[j][0] = ldB(buf, 2+j, 0); b23[j][1] = ldB(buf, 2+j, 1); }
        if (s2)       { stA(buf, kk2, 0, 0); stA(buf, kk2, 0, 1); }
        else if (!s1) { VM0; }
        BARS; SP1;
        #pragma unroll
        for (int i = 0; i < 4; i++)
            #pragma unroll
            for (int j = 0; j < 2; j++)
                #pragma unroll
                for (int kb = 0; kb < 2; kb++)
                    acc[i][2+j] = __builtin_amdgcn_mfma_f32_16x16x32_f16(a[i][kb], b23[j][kb], acc[i][2+j], 0, 0, 0);
        SP0; BARS;

        #pragma unroll
        for (int i = 0; i < 4; i++) { a[i][0] = ldA(buf, 4+i, 0); a[i][1] = ldA(buf, 4+i, 1); }
        if (s2) { stB(buf, kk2, 0, 0); stB(buf, kk2, 0, 1); }
        BARS; SP1;
        #pragma unroll
        for (int i = 0; i < 4; i++)
            #pragma unroll
            for (int j = 0; j < 2; j++)
                #pragma unroll
                for (int kb = 0; kb < 2; kb++)
                    acc[4+i][2+j] = __builtin_amdgcn_mfma_f32_16x16x32_f16(a[i][kb], b23[j][kb], acc[4+i][2+j], 0, 0, 0);
        SP0; BARS;

        if (s2)      { stB(buf, kk2, 1, 0); stB(buf, kk2, 1, 1); VM6; }
        else if (s1) { VM4; }
        BARS; SP1;
        #pragma unroll
        for (int i = 0; i < 4; i++)
            #pragma unroll
            for (int j = 0; j < 2; j++)
                #pragma unroll
                for (int kb = 0; kb < 2; kb++)
                    acc[4+i][j] = __builtin_amdgcn_mfma_f32_16x16x32_f16(a[i][kb], b01[j][kb], acc[4+i][j], 0, 0, 0);
        SP0; BARS;
    }

    #pragma unroll
    for (int i = 0; i < 8; i++) {
        const int ob = m0 + ((i&3)*16) + wr*64 + ((i>>2)*128) + l4*4;
        #pragma unroll
        for (int j = 0; j < 4; j++) {
            const int ncol = n0 + ((j&1)*16) + wc*32 + ((j>>1)*128) + l15;
            f32x4 v = acc[i][j];
            #pragma unroll
            for (int r = 0; r < 4; r++)
                Yb[(size_t)(ob + r) * ostride + ncol] = (f16)v[r];
        }
    }
}

// ---------------------------------------------------------------- split-K reduce: styled = f16(p0+p1)
__global__ __launch_bounds__(256)
void reduce_pv_kernel(const f16* __restrict__ p0, const f16* __restrict__ p1, f16* __restrict__ out)
{
    size_t i = ((size_t)blockIdx.x * 256 + threadIdx.x) * 8;
    half8 a = *(const half8*)(p0 + i);
    half8 b = *(const half8*)(p1 + i);
    half8 o;
    #pragma unroll
    for (int e = 0; e < 8; e++) o[e] = (f16)((float)a[e] + (float)b[e]);
    *(half8*)(out + i) = o;
}

// ---------------------------------------------------------------- row softmax (in place, f16)
__global__ __launch_bounds__(256)
void softmax_kernel(f16* __restrict__ S, int nrows)
{
    int row = blockIdx.x * 4 + (threadIdx.x >> 6);
    if (row >= nrows) return;
    int lane = threadIdx.x & 63;
    f16* p = S + (size_t)row * NSP + lane * 8;

    half8 v[8];
    #pragma unroll
    for (int j = 0; j < 8; j++) v[j] = *(const half8*)(p + j * 512);

    float mx = -1e30f;
    #pragma unroll
    for (int j = 0; j < 8; j++)
        #pragma unroll
        for (int e = 0; e < 8; e++) mx = fmaxf(mx, (float)v[j][e]);
    #pragma unroll
    for (int off = 32; off; off >>= 1) mx = fmaxf(mx, __shfl_xor(mx, off));

    float ex[64];
    float s = 0.f;
    #pragma unroll
    for (int j = 0; j < 8; j++)
        #pragma unroll
        for (int e = 0; e < 8; e++) {
            float x = __expf((float)v[j][e] - mx);
            ex[j*8 + e] = x; s += x;
        }
    #pragma unroll
    for (int off = 32; off; off >>= 1) s += __shfl_xor(s, off);
    float inv = 1.0f / s;

    #pragma unroll
    for (int j = 0; j < 8; j++) {
        half8 o;
        #pragma unroll
        for (int e = 0; e < 8; e++) o[e] = (f16)(ex[j*8 + e] * inv);
        *(half8*)(p + j * 512) = o;
    }
}

// ---------------------------------------------------------------- launch
extern "C" void kernel_launch(void* const* d_in, const int* in_sizes, int n_in,
                              void* d_out, int out_size, void* d_ws, size_t ws_size,
                              hipStream_t stream)
{
    const float* content = (const float*)d_in[0];
    const float* style   = (const float*)d_in[1];
    const float* f_w = (const float*)d_in[2];
    const float* f_b = (const float*)d_in[3];
    const float* g_w = (const float*)d_in[4];
    const float* g_b = (const float*)d_in[5];
    const float* h_w = (const float*)d_in[6];
    const float* h_b = (const float*)d_in[7];
    const float* o_w = (const float*)d_in[8];
    const float* o_b = (const float*)d_in[9];

    char* ws = (char*)d_ws;
    size_t off = 0;
    auto alloc = [&](size_t bytes) -> void* {
        void* p = ws + off;
        off += (bytes + 255) & ~(size_t)255;
        return p;
    };
    float* raw = (float*)alloc(4 * NB*CH * 4);
    f16* fw_e = (f16*)alloc((size_t)NB*CH*CH*2);
    f16* gw_e = (f16*)alloc((size_t)NB*CH*CH*2);
    f16* hw_h = (f16*)alloc((size_t)CH*CH*2);
    f16* ow_h = (f16*)alloc((size_t)CH*CH*2);
    float* fb_e = (float*)alloc((size_t)NB*CH*4);
    float* gb_e = (float*)alloc((size_t)NB*CH*4);
    f16* content_t = (f16*)alloc((size_t)NB*NSP*CH*2);
    f16* style_t   = (f16*)alloc((size_t)NB*NSP*CH*2);
    f16* F_t = (f16*)alloc((size_t)NB*NSP*CH*2);
    f16* G_t = (f16*)alloc((size_t)NB*NSP*CH*2);
    f16* H_  = (f16*)alloc((size_t)NB*CH*NSP*2);
    f16* styled_t = content_t;           // content_t dead after conv3

    size_t s_plane = (size_t)NSP * NSP;
    bool all4 = (off + 4 * s_plane * 2 <= ws_size);
    f16* S16 = (f16*)alloc((all4 ? 4 : 1) * s_plane * 2);
    if (off > ws_size) return;

    hipMemsetAsync(raw, 0, 4 * NB*CH * 4, stream);
    transpose_f16_kernel<<<dim3(NSP/64, CH/64, NB*2), dim3(256), 0, stream>>>(
        content, style, content_t, style_t, raw);
    effw_kernel<<<dim3(CH, NB, 4), dim3(128), 0, stream>>>(f_w, f_b, g_w, g_b, h_w, o_w, raw,
                                                           fw_e, fb_e, gw_e, gb_e, hw_h, ow_h);
    conv3_kernel<<<dim3(12*128), dim3(256), 0, stream>>>(
        fw_e, fb_e, gw_e, gb_e, hw_h, h_b, content_t, style_t, F_t, G_t, H_);

    if (all4) {
        // S16[n][m]: W=G_t (ob=m, 32 mt), Xt=F_t (ncol=n, 16 nt); TPB=512 -> grid 2048, 2 blocks/CU
        gemm_att2_kernel<512,16,1><<<dim3(2048), dim3(256), 0, stream>>>(
            G_t, (long)NSP*CH, F_t, (long)NSP*CH, S16, nullptr, (long)s_plane, CH, CH, (long)NSP);
        softmax_kernel<<<dim3(NB*NSP/4), dim3(256), 0, stream>>>(S16, NB*NSP);
        // PV split-K=2 (proven R10): W=S16 (ob=n), Xt=H_ (ncol=c); 256 blocks
        gemm256_kernel<32,2,2><<<dim3(256), dim3(512), 0, stream>>>(
            S16, (long)s_plane, H_, (long)CH*NSP, F_t, G_t, (long)NSP*CH, NSP/2, NSP, (long)CH);
        reduce_pv_kernel<<<dim3((int)((size_t)NB*NSP*CH/2048)), dim3(256), 0, stream>>>(F_t, G_t, styled_t);
    } else {
        for (int b = 0; b < NB; b++) {
            gemm_att_kernel<1024,32><<<dim3(1024), dim3(256), 0, stream>>>(
                F_t + (size_t)b*NSP*CH, 0L, G_t + (size_t)b*NSP*CH, 0L,
                S16, 0L, CH, (long)NSP);
            softmax_kernel<<<dim3(NSP/4), dim3(256), 0, stream>>>(S16, NSP);
            gemm_att_kernel<128,4><<<dim3(128), dim3(256), 0, stream>>>(
                S16, 0L, H_ + (size_t)b*CH*NSP, 0L,
                styled_t + (size_t)b*NSP*CH, 0L, NSP, (long)CH);
        }
    }

    // out = conv1x1(styled): f32 output
    gemm_kernel<2><<<dim3(NSP/128, CH/128, NB), dim3(256), 0, stream>>>(
        ow_h, 0L, styled_t, (long)NSP*CH, o_b, 0L, d_out, (long)CH*NSP, CH, (long)NSP);
}

// Round 12
// 297.933 us; speedup vs baseline: 1.2316x; 1.2316x over previous
//
#include <hip/hip_runtime.h>
#include <hip/hip_bf16.h>

typedef _Float16 f16;
typedef __attribute__((ext_vector_type(8))) _Float16 half8;
typedef __attribute__((ext_vector_type(4))) _Float16 half4;
typedef __attribute__((ext_vector_type(4))) float f32x4;

#define AS1 __attribute__((address_space(1)))
#define AS3 __attribute__((address_space(3)))

constexpr int CH  = 512;    // channels
constexpr int NSP = 4096;   // 64*64 spatial
constexpr int NB  = 4;      // batch

#define VM8  asm volatile("s_waitcnt vmcnt(8)"  ::: "memory")
#define VM6  asm volatile("s_waitcnt vmcnt(6)"  ::: "memory")
#define VM4  asm volatile("s_waitcnt vmcnt(4)"  ::: "memory")
#define VM2  asm volatile("s_waitcnt vmcnt(2)"  ::: "memory")
#define VM0  asm volatile("s_waitcnt vmcnt(0)"  ::: "memory")
#define BARS do { __builtin_amdgcn_s_barrier(); asm volatile("" ::: "memory"); } while (0)
#define SP1  __builtin_amdgcn_s_setprio(1)
#define SP0  __builtin_amdgcn_s_setprio(0)

__device__ __forceinline__ void gload_lds16(const void* g, void* l) {
    __builtin_amdgcn_global_load_lds((const AS1 void*)g, (AS3 void*)l, 16, 0, 0);
}

// ---------------------------------------------------------------- transpose f32[c][n] -> f16[n][c] + fused stats
__global__ void transpose_f16_kernel(const float* __restrict__ content, const float* __restrict__ style,
                                     f16* __restrict__ content_t, f16* __restrict__ style_t,
                                     float* __restrict__ raw)
{
    int b = blockIdx.z & 3, is_style = blockIdx.z >> 2;
    const float* src = (is_style ? style : content) + (size_t)b * CH * NSP;
    f16* dst = (is_style ? style_t : content_t) + (size_t)b * NSP * CH;
    int c0 = blockIdx.y * 64, n0 = blockIdx.x * 64;
    __shared__ f16 tile[64][72];
    int t = threadIdx.x;
    #pragma unroll
    for (int i = 0; i < 4; i++) {
        int idx = t + i*256;
        int cr = idx >> 4, n4 = (idx & 15) * 4;
        float4 v = *(const float4*)(src + (size_t)(c0+cr)*NSP + n0 + n4);
        tile[cr][n4+0] = (f16)v.x; tile[cr][n4+1] = (f16)v.y;
        tile[cr][n4+2] = (f16)v.z; tile[cr][n4+3] = (f16)v.w;
    }
    __syncthreads();
    {
        int row = t >> 2, seg = (t & 3) * 16;
        float s1 = 0.f, s2 = 0.f;
        #pragma unroll
        for (int j = 0; j < 16; j++) {
            float x = (float)tile[row][seg + j];
            s1 += x; s2 += x * x;
        }
        s1 += __shfl_down(s1, 2, 4); s1 += __shfl_down(s1, 1, 4);
        s2 += __shfl_down(s2, 2, 4); s2 += __shfl_down(s2, 1, 4);
        if ((t & 3) == 0) {
            int si = is_style * 2 * NB * CH + b * CH + c0 + row;
            atomicAdd(&raw[si], s1);
            atomicAdd(&raw[si + NB * CH], s2);
        }
    }
    int nr = t >> 2, seg = (t & 3) * 16;
    __align__(16) f16 out_v[16];
    #pragma unroll
    for (int j = 0; j < 16; j++) out_v[j] = tile[seg + j][nr];
    f16* dp = dst + (size_t)(n0+nr)*CH + c0 + seg;
    *(int4*)dp = ((int4*)out_v)[0];
    *(int4*)(dp + 8) = ((int4*)out_v)[1];
}

// ---------------------------------------------------------------- effective weights (from raw sums)
__global__ void effw_kernel(const float* __restrict__ fw, const float* __restrict__ fb,
                            const float* __restrict__ gw, const float* __restrict__ gb,
                            const float* __restrict__ hw, const float* __restrict__ ow,
                            const float* __restrict__ raw,
                            f16* __restrict__ fw_e, float* __restrict__ fb_e,
                            f16* __restrict__ gw_e, float* __restrict__ gb_e,
                            f16* __restrict__ hw_h, f16* __restrict__ ow_h)
{
    int o = blockIdx.x, b = blockIdx.y, mode = blockIdx.z, t = threadIdx.x;
    if (mode >= 2) {
        if (b != 0) return;
        const float* srcw = (mode == 2) ? hw : ow;
        f16* dstw = (mode == 2) ? hw_h : ow_h;
        for (int c = t; c < CH; c += 128) dstw[o*CH + c] = (f16)srcw[o*CH + c];
        return;
    }
    const float* w  = mode ? gw : fw;
    const float* rw = raw + (mode ? 2*NB*CH : 0);
    f16* we = mode ? gw_e : fw_e;
    float part = 0.f;
    for (int c = t; c < CH; c += 128) {
        float s1 = rw[b*CH + c], s2 = rw[NB*CH + b*CH + c];
        float mn = s1 * (1.f/NSP);
        float var = (s2 - (float)NSP*mn*mn) * (1.f/(NSP-1));
        float is = rsqrtf(var + 1e-5f);
        float wv = w[o*CH + c];
        we[((size_t)b*CH + o)*CH + c] = (f16)(wv * is);
        part += wv * mn * is;
    }
    #pragma unroll
    for (int off = 32; off; off >>= 1) part += __shfl_down(part, off);
    __shared__ float rr[2];
    if ((t & 63) == 0) rr[t >> 6] = part;
    __syncthreads();
    if (t == 0) (mode ? gb_e : fb_e)[b*CH + o] = (mode ? gb : fb)[o] - (rr[0] + rr[1]);
}

// ---------------------------------------------------------------- fused F/G/H conv GEMM (K=512), m97-style
__global__ __launch_bounds__(256)
void conv3_kernel(const f16* __restrict__ fw_e, const float* __restrict__ fb_e,
                  const f16* __restrict__ gw_e, const float* __restrict__ gb_e,
                  const f16* __restrict__ hw_h, const float* __restrict__ h_b,
                  const f16* __restrict__ content_t, const f16* __restrict__ style_t,
                  f16* __restrict__ F_t, f16* __restrict__ G_t, f16* __restrict__ H_)
{
    const int T = gridDim.x;   // 1536
    const int bid = blockIdx.x;
    const int tile = (bid & 7) * (T >> 3) + (bid >> 3);
    const int zz = tile >> 7, rem = tile & 127;
    const int mt = rem >> 5, nt = rem & 31;
    const int kind = zz >> 2, b = zz & 3;

    const f16* W; const float* bias; const f16* Xt; f16* Y;
    if (kind == 0)      { W = fw_e + (size_t)b*CH*CH; bias = fb_e + b*CH; Xt = content_t + (size_t)b*NSP*CH; Y = F_t + (size_t)b*NSP*CH; }
    else if (kind == 1) { W = gw_e + (size_t)b*CH*CH; bias = gb_e + b*CH; Xt = style_t + (size_t)b*NSP*CH; Y = G_t + (size_t)b*NSP*CH; }
    else                { W = hw_h;                    bias = h_b;         Xt = style_t + (size_t)b*NSP*CH; Y = H_ + (size_t)b*CH*NSP; }

    const int m0 = mt * 128, n0 = nt * 128;
    const int t = threadIdx.x, wave = t >> 6, lane = t & 63;
    const int l15 = lane & 15, l4 = lane >> 4;
    const int wm = (wave >> 1) * 64, wn = (wave & 1) * 64;

    __shared__ __align__(16) f16 Al[8192];
    __shared__ __align__(16) f16 Bl[8192];

    f32x4 acc[4][4] = {};

    for (int ks = 0; ks < CH/64; ks++) {
        const int kk = ks * 64;
        #pragma unroll
        for (int j = 0; j < 4; j++) {
            int L  = ((wave*4 + j)*64 + lane) * 16;
            int SL = L ^ (((L >> 7) & 7) << 4);
            int row = SL >> 7, seg = (SL & 127) >> 1;
            gload_lds16(W  + (size_t)(m0 + row)*CH + kk + seg, &Al[L >> 1]);
            gload_lds16(Xt + (size_t)(n0 + row)*CH + kk + seg, &Bl[L >> 1]);
        }
        VM0; BARS;
        #pragma unroll
        for (int kb = 0; kb < 2; kb++) {
            half8 a[4], bb[4];
            #pragma unroll
            for (int i = 0; i < 4; i++) {
                int ab = (wm + i*16 + l15)*128 + kb*64 + l4*16;
                ab ^= ((ab >> 7) & 7) << 4;
                a[i] = *(const half8*)&Al[ab >> 1];
                int bby = (wn + i*16 + l15)*128 + kb*64 + l4*16;
                bby ^= ((bby >> 7) & 7) << 4;
                bb[i] = *(const half8*)&Bl[bby >> 1];
            }
            #pragma unroll
            for (int i = 0; i < 4; i++)
                #pragma unroll
                for (int jj = 0; jj < 4; jj++)
                    acc[i][jj] = __builtin_amdgcn_mfma_f32_16x16x32_f16(a[i], bb[jj], acc[i][jj], 0, 0, 0);
        }
        BARS;
    }

    #pragma unroll
    for (int i = 0; i < 4; i++) {
        const int ob = m0 + wm + i*16 + l4*4;
        f32x4 bv = *(const f32x4*)(bias + ob);
        #pragma unroll
        for (int jj = 0; jj < 4; jj++) {
            const int n = n0 + wn + jj*16 + l15;
            f32x4 v = acc[i][jj];
            v[0] += bv[0]; v[1] += bv[1]; v[2] += bv[2]; v[3] += bv[3];
            if (kind < 2) {
                half4 pk; pk[0]=(f16)v[0]; pk[1]=(f16)v[1]; pk[2]=(f16)v[2]; pk[3]=(f16)v[3];
                *(half4*)(Y + (size_t)n * CH + ob) = pk;
            } else {
                #pragma unroll
                for (int r = 0; r < 4; r++) Y[(size_t)(ob + r) * NSP + n] = (f16)v[r];
            }
        }
    }
}

// ---------------------------------------------------------------- 128x128 GEMM (out conv, fallback), proven R3
template<int MODE>   // 2: f32 Y[ob][n]
__global__ __launch_bounds__(256)
void gemm_kernel(const f16* __restrict__ W, long wstrideb,
                 const f16* __restrict__ Xt, long xstrideb,
                 const float* __restrict__ bias, long bstrideb,
                 void* __restrict__ Y, long ystrideb,
                 int K, long ostride)
{
    const int z = blockIdx.z;
    W    += (size_t)z * wstrideb;
    Xt   += (size_t)z * xstrideb;
    bias += (size_t)z * bstrideb;
    const int m0 = blockIdx.y * 128, n0 = blockIdx.x * 128;
    const int t = threadIdx.x, wave = t >> 6, lane = t & 63;
    const int l15 = lane & 15, l4 = lane >> 4;
    const int wm = (wave >> 1) * 64, wn = (wave & 1) * 64;

    __shared__ __align__(16) f16 Al[2][8192];
    __shared__ __align__(16) f16 Bl[2][8192];

    f32x4 acc[4][4] = {};

    auto stage = [&](int bufi, int kk) {
        #pragma unroll
        for (int j = 0; j < 4; j++) {
            int L  = ((wave*4 + j)*64 + lane) * 16;
            int SL = L ^ (((L >> 7) & 7) << 4);
            int row = SL >> 7, seg = (SL & 127) >> 1;
            gload_lds16(W  + (size_t)(m0 + row)*K + kk + seg, &Al[bufi][L >> 1]);
            gload_lds16(Xt + (size_t)(n0 + row)*K + kk + seg, &Bl[bufi][L >> 1]);
        }
    };

    const int nks = K >> 6;
    stage(0, 0);
    for (int ks = 0; ks < nks; ks++) {
        int bufi = ks & 1;
        if (ks < nks-1) { stage(bufi ^ 1, (ks + 1) * 64); VM8; }
        else            { VM0; }
        BARS;
        #pragma unroll
        for (int kb = 0; kb < 2; kb++) {
            half8 a[4], bb[4];
            #pragma unroll
            for (int i = 0; i < 4; i++) {
                int ab = (wm + i*16 + l15)*128 + kb*64 + l4*16;
                ab ^= ((ab >> 7) & 7) << 4;
                a[i] = *(const half8*)&Al[bufi][ab >> 1];
                int bby = (wn + i*16 + l15)*128 + kb*64 + l4*16;
                bby ^= ((bby >> 7) & 7) << 4;
                bb[i] = *(const half8*)&Bl[bufi][bby >> 1];
            }
            #pragma unroll
            for (int i = 0; i < 4; i++)
                #pragma unroll
                for (int jj = 0; jj < 4; jj++)
                    acc[i][jj] = __builtin_amdgcn_mfma_f32_16x16x32_f16(a[i], bb[jj], acc[i][jj], 0, 0, 0);
        }
        BARS;
    }

    #pragma unroll
    for (int i = 0; i < 4; i++) {
        const int ob = m0 + wm + i*16 + l4*4;
        f32x4 bv = *(const f32x4*)(bias + ob);
        #pragma unroll
        for (int jj = 0; jj < 4; jj++) {
            const int n = n0 + wn + jj*16 + l15;
            f32x4 v = acc[i][jj];
            v[0] += bv[0]; v[1] += bv[1]; v[2] += bv[2]; v[3] += bv[3];
            float* Yf = (float*)Y + (size_t)z * ystrideb;
            #pragma unroll
            for (int r = 0; r < 4; r++) Yf[(size_t)(ob + r) * ostride + n] = v[r];
        }
    }
}

// ---------------------------------------------------------------- fused out conv: Y[o][n] = sum_c ow[o][c]*(P0[n][c]+P1[n][c]) + o_b[o]
// B staged manually (reg add in f32 -> swizzled ds_write_b128); A via gload_lds. Single-buffer m97 loop.
__global__ __launch_bounds__(256)
void out_fused_kernel(const f16* __restrict__ W, const f16* __restrict__ P0, const f16* __restrict__ P1,
                      const float* __restrict__ bias, float* __restrict__ Y)
{
    const int z = blockIdx.z;
    const f16* p0 = P0 + (size_t)z * NSP * CH;
    const f16* p1 = P1 + (size_t)z * NSP * CH;
    float* Yf = Y + (size_t)z * CH * NSP;
    const int m0 = blockIdx.y * 128, n0 = blockIdx.x * 128;
    const int t = threadIdx.x, wave = t >> 6, lane = t & 63;
    const int l15 = lane & 15, l4 = lane >> 4;
    const int wm = (wave >> 1) * 64, wn = (wave & 1) * 64;

    __shared__ __align__(16) f16 Al[8192];
    __shared__ __align__(16) f16 Bl[8192];

    f32x4 acc[4][4] = {};

    for (int ks = 0; ks < CH/64; ks++) {
        const int kk = ks * 64;
        int Ls[4];
        half8 b0[4], b1[4];
        #pragma unroll
        for (int j = 0; j < 4; j++) {
            int L  = ((wave*4 + j)*64 + lane) * 16;
            int SL = L ^ (((L >> 7) & 7) << 4);
            int row = SL >> 7, seg = (SL & 127) >> 1;
            gload_lds16(W + (size_t)(m0 + row)*CH + kk + seg, &Al[L >> 1]);
            b0[j] = *(const half8*)(p0 + (size_t)(n0 + row)*CH + kk + seg);
            b1[j] = *(const half8*)(p1 + (size_t)(n0 + row)*CH + kk + seg);
            Ls[j] = L;
        }
        #pragma unroll
        for (int j = 0; j < 4; j++) {
            half8 s;
            #pragma unroll
            for (int e = 0; e < 8; e++) s[e] = (f16)((float)b0[j][e] + (float)b1[j][e]);
            *(half8*)&Bl[Ls[j] >> 1] = s;
        }
        __syncthreads();    // drains vmcnt (gload_lds) + lgkm (ds_write) per syncthreads semantics
        #pragma unroll
        for (int kb = 0; kb < 2; kb++) {
            half8 a[4], bb[4];
            #pragma unroll
            for (int i = 0; i < 4; i++) {
                int ab = (wm + i*16 + l15)*128 + kb*64 + l4*16;
                ab ^= ((ab >> 7) & 7) << 4;
                a[i] = *(const half8*)&Al[ab >> 1];
                int bby = (wn + i*16 + l15)*128 + kb*64 + l4*16;
                bby ^= ((bby >> 7) & 7) << 4;
                bb[i] = *(const half8*)&Bl[bby >> 1];
            }
            #pragma unroll
            for (int i = 0; i < 4; i++)
                #pragma unroll
                for (int jj = 0; jj < 4; jj++)
                    acc[i][jj] = __builtin_amdgcn_mfma_f32_16x16x32_f16(a[i], bb[jj], acc[i][jj], 0, 0, 0);
        }
        __syncthreads();
    }

    #pragma unroll
    for (int i = 0; i < 4; i++) {
        const int ob = m0 + wm + i*16 + l4*4;
        f32x4 bv = *(const f32x4*)(bias + ob);
        #pragma unroll
        for (int jj = 0; jj < 4; jj++) {
            const int n = n0 + wn + jj*16 + l15;
            f32x4 v = acc[i][jj];
            #pragma unroll
            for (int r = 0; r < 4; r++) Yf[(size_t)(ob + r) * NSP + n] = v[r] + bv[r];
        }
    }
}

// ---------------------------------------------------------------- attention GEMM fallback (m97-style)
template<int TPB, int NCT>
__global__ __launch_bounds__(256)
void gemm_att_kernel(const f16* __restrict__ W, long wstrideb,
                     const f16* __restrict__ Xt, long xstrideb,
                     f16* __restrict__ Y, long ystrideb,
                     int K, long ostride)
{
    const int T = gridDim.x;
    const int bid = blockIdx.x;
    const int tile = (bid & 7) * (T >> 3) + (bid >> 3);
    const int z = tile / TPB, rem = tile - z * TPB;
    const int mt = rem / NCT, nt = rem - mt * NCT;
    W  += (size_t)z * wstrideb;
    Xt += (size_t)z * xstrideb;
    f16* Yb = Y + (size_t)z * ystrideb;
    const int m0 = mt * 128, n0 = nt * 128;

    const int t = threadIdx.x, wave = t >> 6, lane = t & 63;
    const int l15 = lane & 15, l4 = lane >> 4;
    const int wm = (wave >> 1) * 64, wn = (wave & 1) * 64;

    __shared__ __align__(16) f16 Al[8192];
    __shared__ __align__(16) f16 Bl[8192];

    f32x4 acc[4][4] = {};

    const int nks = K >> 6;
    for (int ks = 0; ks < nks; ks++) {
        const int kk = ks * 64;
        #pragma unroll
        for (int j = 0; j < 4; j++) {
            int L  = ((wave*4 + j)*64 + lane) * 16;
            int SL = L ^ (((L >> 7) & 7) << 4);
            int row = SL >> 7, seg = (SL & 127) >> 1;
            gload_lds16(W  + (size_t)(m0 + row)*K + kk + seg, &Al[L >> 1]);
            gload_lds16(Xt + (size_t)(n0 + row)*K + kk + seg, &Bl[L >> 1]);
        }
        VM0; BARS;
        #pragma unroll
        for (int kb = 0; kb < 2; kb++) {
            half8 a[4], bb[4];
            #pragma unroll
            for (int i = 0; i < 4; i++) {
                int ab = (wm + i*16 + l15)*128 + kb*64 + l4*16;
                ab ^= ((ab >> 7) & 7) << 4;
                a[i] = *(const half8*)&Al[ab >> 1];
                int bby = (wn + i*16 + l15)*128 + kb*64 + l4*16;
                bby ^= ((bby >> 7) & 7) << 4;
                bb[i] = *(const half8*)&Bl[bby >> 1];
            }
            #pragma unroll
            for (int i = 0; i < 4; i++)
                #pragma unroll
                for (int jj = 0; jj < 4; jj++)
                    acc[i][jj] = __builtin_amdgcn_mfma_f32_16x16x32_f16(a[i], bb[jj], acc[i][jj], 0, 0, 0);
        }
        BARS;
    }

    #pragma unroll
    for (int i = 0; i < 4; i++) {
        const int ob = m0 + wm + i*16 + l4*4;
        #pragma unroll
        for (int jj = 0; jj < 4; jj++) {
            const int ncol = n0 + wn + jj*16 + l15;
            #pragma unroll
            for (int r = 0; r < 4; r++)
                Yb[(size_t)(ob + r) * ostride + ncol] = (f16)acc[i][jj][r];
        }
    }
}

// ---------------------------------------------------------------- 256x256 8-phase GEMM (m201-faithful, proven R10)
// MODET 0: f16 row store Y[ob][ncol]; MODET 1: f16 transposed half4 store Y[ncol][ob]
template<int TPB, int NCT, int SPLITK, int MODET = 0>
__global__ __launch_bounds__(512)
void gemm256_kernel(const f16* __restrict__ W, long wstrideb,
                    const f16* __restrict__ Xt, long xstrideb,
                    f16* __restrict__ Y0, f16* __restrict__ Y1, long ystrideb,
                    int K, int kstride, long ostride)
{
    const int T = gridDim.x;
    const int bid = blockIdx.x;
    const int tile = (bid & 7) * (T >> 3) + (bid >> 3);
    int rem = tile, sp = 0;
    if constexpr (SPLITK == 2) { sp = tile / (NB * TPB); rem = tile - sp * NB * TPB; }
    const int z = rem / TPB; rem -= z * TPB;
    const int mt = rem / NCT, nt = rem - mt * NCT;
    const f16* Wb = W  + (size_t)z * wstrideb + (size_t)sp * K;
    const f16* Xb = Xt + (size_t)z * xstrideb + (size_t)sp * K;
    f16* Yb = ((SPLITK == 2 && sp) ? Y1 : Y0) + (size_t)z * ystrideb;
    const int m0 = mt * 256, n0 = nt * 256;

    const int t = threadIdx.x, lane = t & 63, wave = t >> 6;
    const int l15 = lane & 15, l4 = lane >> 4;
    const int wr = wave >> 2, wc = wave & 3;

    __shared__ __align__(16) f16 As[2][16384];
    __shared__ __align__(16) f16 Bs[2][16384];

    f32x4 acc[8][4] = {};

    auto stA = [&](int nbuf, int kk, int half, int q) {
        int L  = half*16384 + q*8192 + t*16;
        int SL = L ^ (((L >> 7) & 7) << 4);
        gload_lds16(Wb + (size_t)(m0 + (SL >> 7)) * kstride + kk + ((SL & 127) >> 1), &As[nbuf][L >> 1]);
    };
    auto stB = [&](int nbuf, int kk, int half, int q) {
        int L  = half*16384 + q*8192 + t*16;
        int SL = L ^ (((L >> 7) & 7) << 4);
        gload_lds16(Xb + (size_t)(n0 + (SL >> 7)) * kstride + kk + ((SL & 127) >> 1), &Bs[nbuf][L >> 1]);
    };
    auto ldA = [&](int buf, int i, int kb) {
        int L = (((i&3)*16) + wr*64 + ((i>>2)*128) + l15)*128 + kb*64 + l4*16;
        L ^= ((L >> 7) & 7) << 4;
        return *(const half8*)&As[buf][L >> 1];
    };
    auto ldB = [&](int buf, int j, int kb) {
        int L = (((j&1)*16) + wc*32 + ((j>>1)*128) + l15)*128 + kb*64 + l4*16;
        L ^= ((L >> 7) & 7) << 4;
        return *(const half8*)&Bs[buf][L >> 1];
    };

    const int nks = K >> 6;
    stA(0,0,0,0); stA(0,0,0,1);
    stB(0,0,0,0); stB(0,0,0,1);
    stB(0,0,1,0); stB(0,0,1,1);
    stA(0,0,1,0); stA(0,0,1,1);
    VM4;
    if (nks > 1) {
        stA(1,64,0,0); stA(1,64,0,1);
        stB(1,64,0,0); stB(1,64,0,1);
        stB(1,64,1,0); stB(1,64,1,1);
        VM6;
    } else { VM0; }
    BARS;

    half8 a[4][2], b01[2][2], b23[2][2];

    for (int kt = 0; kt < nks; kt++) {
        const int buf = kt & 1;
        const int kk1 = (kt+1) << 6, kk2 = (kt+2) << 6;
        const bool s1 = (kt+1 < nks), s2 = (kt+2 < nks);

        // ---- p1: reads A0(i0-3)+B0(j0-1); stage t+1.A1 -> buf^1
        #pragma unroll
        for (int i = 0; i < 4; i++) { a[i][0] = ldA(buf, i, 0); a[i][1] = ldA(buf, i, 1); }
        #pragma unroll
        for (int j = 0; j < 2; j++) { b01[j][0] = ldB(buf, j, 0); b01[j][1] = ldB(buf, j, 1); }
        if (s1) { stA(buf^1, kk1, 1, 0); stA(buf^1, kk1, 1, 1); }
        else    { VM2; }
        BARS; SP1;
        #pragma unroll
        for (int i = 0; i < 4; i++)
            #pragma unroll
            for (int j = 0; j < 2; j++)
                #pragma unroll
                for (int kb = 0; kb < 2; kb++)
                    acc[i][j] = __builtin_amdgcn_mfma_f32_16x16x32_f16(a[i][kb], b01[j][kb], acc[i][j], 0, 0, 0);
        SP0; BARS;

        // ---- p2: reads B1(j2-3); stage t+2.A0 -> buf
        #pragma unroll
        for (int j = 0; j < 2; j++) { b23[j][0] = ldB(buf, 2+j, 0); b23[j][1] = ldB(buf, 2+j, 1); }
        if (s2)       { stA(buf, kk2, 0, 0); stA(buf, kk2, 0, 1); }
        else if (!s1) { VM0; }
        BARS; SP1;
        #pragma unroll
        for (int i = 0; i < 4; i++)
            #pragma unroll
            for (int j = 0; j < 2; j++)
                #pragma unroll
                for (int kb = 0; kb < 2; kb++)
                    acc[i][2+j] = __builtin_amdgcn_mfma_f32_16x16x32_f16(a[i][kb], b23[j][kb], acc[i][2+j], 0, 0, 0);
        SP0; BARS;

        // ---- p3: reads A1(i4-7); stage t+2.B0 -> buf
        #pragma unroll
        for (int i = 0; i < 4; i++) { a[i][0] = ldA(buf, 4+i, 0); a[i][1] = ldA(buf, 4+i, 1); }
        if (s2) { stB(buf, kk2, 0, 0); stB(buf, kk2, 0, 1); }
        BARS; SP1;
        #pragma unroll
        for (int i = 0; i < 4; i++)
            #pragma unroll
            for (int j = 0; j < 2; j++)
                #pragma unroll
                for (int kb = 0; kb < 2; kb++)
                    acc[4+i][2+j] = __builtin_amdgcn_mfma_f32_16x16x32_f16(a[i][kb], b23[j][kb], acc[4+i][2+j], 0, 0, 0);
        SP0; BARS;

        // ---- p4: no new reads; stage t+2.B1 -> buf; K-tile wait
        if (s2)      { stB(buf, kk2, 1, 0); stB(buf, kk2, 1, 1); VM6; }
        else if (s1) { VM4; }
        BARS; SP1;
        #pragma unroll
        for (int i = 0; i < 4; i++)
            #pragma unroll
            for (int j = 0; j < 2; j++)
                #pragma unroll
                for (int kb = 0; kb < 2; kb++)
                    acc[4+i][j] = __builtin_amdgcn_mfma_f32_16x16x32_f16(a[i][kb], b01[j][kb], acc[4+i][j], 0, 0, 0);
        SP0; BARS;
    }

    #pragma unroll
    for (int i = 0; i < 8; i++) {
        const int ob = m0 + ((i&3)*16) + wr*64 + ((i>>2)*128) + l4*4;
        #pragma unroll
        for (int j = 0; j < 4; j++) {
            const int ncol = n0 + ((j&1)*16) + wc*32 + ((j>>1)*128) + l15;
            f32x4 v = acc[i][j];
            if constexpr (MODET) {
                half4 pk; pk[0]=(f16)v[0]; pk[1]=(f16)v[1]; pk[2]=(f16)v[2]; pk[3]=(f16)v[3];
                *(half4*)(Yb + (size_t)ncol * ostride + ob) = pk;
            } else {
                #pragma unroll
                for (int r = 0; r < 4; r++)
                    Yb[(size_t)(ob + r) * ostride + ncol] = (f16)v[r];
            }
        }
    }
}

// ---------------------------------------------------------------- row softmax (in place, f16)
__global__ __launch_bounds__(256)
void softmax_kernel(f16* __restrict__ S, int nrows)
{
    int row = blockIdx.x * 4 + (threadIdx.x >> 6);
    if (row >= nrows) return;
    int lane = threadIdx.x & 63;
    f16* p = S + (size_t)row * NSP + lane * 8;

    half8 v[8];
    #pragma unroll
    for (int j = 0; j < 8; j++) v[j] = *(const half8*)(p + j * 512);

    float mx = -1e30f;
    #pragma unroll
    for (int j = 0; j < 8; j++)
        #pragma unroll
        for (int e = 0; e < 8; e++) mx = fmaxf(mx, (float)v[j][e]);
    #pragma unroll
    for (int off = 32; off; off >>= 1) mx = fmaxf(mx, __shfl_xor(mx, off));

    float ex[64];
    float s = 0.f;
    #pragma unroll
    for (int j = 0; j < 8; j++)
        #pragma unroll
        for (int e = 0; e < 8; e++) {
            float x = __expf((float)v[j][e] - mx);
            ex[j*8 + e] = x; s += x;
        }
    #pragma unroll
    for (int off = 32; off; off >>= 1) s += __shfl_xor(s, off);
    float inv = 1.0f / s;

    #pragma unroll
    for (int j = 0; j < 8; j++) {
        half8 o;
        #pragma unroll
        for (int e = 0; e < 8; e++) o[e] = (f16)(ex[j*8 + e] * inv);
        *(half8*)(p + j * 512) = o;
    }
}

// ---------------------------------------------------------------- launch
extern "C" void kernel_launch(void* const* d_in, const int* in_sizes, int n_in,
                              void* d_out, int out_size, void* d_ws, size_t ws_size,
                              hipStream_t stream)
{
    const float* content = (const float*)d_in[0];
    const float* style   = (const float*)d_in[1];
    const float* f_w = (const float*)d_in[2];
    const float* f_b = (const float*)d_in[3];
    const float* g_w = (const float*)d_in[4];
    const float* g_b = (const float*)d_in[5];
    const float* h_w = (const float*)d_in[6];
    const float* h_b = (const float*)d_in[7];
    const float* o_w = (const float*)d_in[8];
    const float* o_b = (const float*)d_in[9];

    char* ws = (char*)d_ws;
    size_t off = 0;
    auto alloc = [&](size_t bytes) -> void* {
        void* p = ws + off;
        off += (bytes + 255) & ~(size_t)255;
        return p;
    };
    float* raw = (float*)alloc(4 * NB*CH * 4);
    f16* fw_e = (f16*)alloc((size_t)NB*CH*CH*2);
    f16* gw_e = (f16*)alloc((size_t)NB*CH*CH*2);
    f16* hw_h = (f16*)alloc((size_t)CH*CH*2);
    f16* ow_h = (f16*)alloc((size_t)CH*CH*2);
    float* fb_e = (float*)alloc((size_t)NB*CH*4);
    float* gb_e = (float*)alloc((size_t)NB*CH*4);
    f16* content_t = (f16*)alloc((size_t)NB*NSP*CH*2);
    f16* style_t   = (f16*)alloc((size_t)NB*NSP*CH*2);
    f16* F_t = (f16*)alloc((size_t)NB*NSP*CH*2);
    f16* G_t = (f16*)alloc((size_t)NB*NSP*CH*2);
    f16* H_  = (f16*)alloc((size_t)NB*CH*NSP*2);
    f16* styled_t = content_t;           // fallback path only

    size_t s_plane = (size_t)NSP * NSP;
    bool all4 = (off + 4 * s_plane * 2 <= ws_size);
    f16* S16 = (f16*)alloc((all4 ? 4 : 1) * s_plane * 2);
    if (off > ws_size) return;

    hipMemsetAsync(raw, 0, 4 * NB*CH * 4, stream);
    transpose_f16_kernel<<<dim3(NSP/64, CH/64, NB*2), dim3(256), 0, stream>>>(
        content, style, content_t, style_t, raw);
    effw_kernel<<<dim3(CH, NB, 4), dim3(128), 0, stream>>>(f_w, f_b, g_w, g_b, h_w, o_w, raw,
                                                           fw_e, fb_e, gw_e, gb_e, hw_h, ow_h);
    conv3_kernel<<<dim3(12*128), dim3(256), 0, stream>>>(
        fw_e, fb_e, gw_e, gb_e, hw_h, h_b, content_t, style_t, F_t, G_t, H_);

    if (all4) {
        // S16[n][m]: W=G_t (ob=m), Xt=F_t (ncol=n), MODET=1 transposed half4 store; 16x16 tiles x 4 b
        gemm256_kernel<256,16,1,1><<<dim3(1024), dim3(512), 0, stream>>>(
            G_t, (long)NSP*CH, F_t, (long)NSP*CH, S16, nullptr, (long)s_plane, CH, CH, (long)NSP);
        softmax_kernel<<<dim3(NB*NSP/4), dim3(256), 0, stream>>>(S16, NB*NSP);
        // PV split-K=2 (proven R10): W=S16 (ob=n), Xt=H_ (ncol=c); partials into F_t/G_t
        gemm256_kernel<32,2,2><<<dim3(256), dim3(512), 0, stream>>>(
            S16, (long)s_plane, H_, (long)CH*NSP, F_t, G_t, (long)NSP*CH, NSP/2, NSP, (long)CH);
        // fused out conv: reads P0,P1 directly (f32 add), writes f32 d_out
        out_fused_kernel<<<dim3(NSP/128, CH/128, NB), dim3(256), 0, stream>>>(
            ow_h, F_t, G_t, o_b, (float*)d_out);
    } else {
        for (int b = 0; b < NB; b++) {
            gemm_att_kernel<1024,32><<<dim3(1024), dim3(256), 0, stream>>>(
                F_t + (size_t)b*NSP*CH, 0L, G_t + (size_t)b*NSP*CH, 0L,
                S16, 0L, CH, (long)NSP);
            softmax_kernel<<<dim3(NSP/4), dim3(256), 0, stream>>>(S16, NSP);
            gemm_att_kernel<128,4><<<dim3(128), dim3(256), 0, stream>>>(
                S16, 0L, H_ + (size_t)b*CH*NSP, 0L,
                styled_t + (size_t)b*NSP*CH, 0L, NSP, (long)CH);
        }
        gemm_kernel<2><<<dim3(NSP/128, CH/128, NB), dim3(256), 0, stream>>>(
            ow_h, 0L, styled_t, (long)NSP*CH, o_b, 0L, d_out, (long)CH*NSP, CH, (long)NSP);
    }
}

// Round 13
// 285.384 us; speedup vs baseline: 1.2858x; 1.0440x over previous
//
#include <hip/hip_runtime.h>
#include <hip/hip_bf16.h>

typedef _Float16 f16;
typedef __attribute__((ext_vector_type(8))) _Float16 half8;
typedef __attribute__((ext_vector_type(4))) _Float16 half4;
typedef __attribute__((ext_vector_type(4))) float f32x4;

#define AS1 __attribute__((address_space(1)))
#define AS3 __attribute__((address_space(3)))

constexpr int CH  = 512;    // channels
constexpr int NSP = 4096;   // 64*64 spatial
constexpr int NB  = 4;      // batch

#define VM8  asm volatile("s_waitcnt vmcnt(8)"  ::: "memory")
#define VM6  asm volatile("s_waitcnt vmcnt(6)"  ::: "memory")
#define VM4  asm volatile("s_waitcnt vmcnt(4)"  ::: "memory")
#define VM2  asm volatile("s_waitcnt vmcnt(2)"  ::: "memory")
#define VM0  asm volatile("s_waitcnt vmcnt(0)"  ::: "memory")
#define BARS do { __builtin_amdgcn_s_barrier(); asm volatile("" ::: "memory"); } while (0)
#define SP1  __builtin_amdgcn_s_setprio(1)
#define SP0  __builtin_amdgcn_s_setprio(0)

__device__ __forceinline__ void gload_lds16(const void* g, void* l) {
    __builtin_amdgcn_global_load_lds((const AS1 void*)g, (AS3 void*)l, 16, 0, 0);
}

// ---------------------------------------------------------------- transpose f32[c][n] -> f16[n][c] + fused stats
__global__ void transpose_f16_kernel(const float* __restrict__ content, const float* __restrict__ style,
                                     f16* __restrict__ content_t, f16* __restrict__ style_t,
                                     float* __restrict__ raw)
{
    int b = blockIdx.z & 3, is_style = blockIdx.z >> 2;
    const float* src = (is_style ? style : content) + (size_t)b * CH * NSP;
    f16* dst = (is_style ? style_t : content_t) + (size_t)b * NSP * CH;
    int c0 = blockIdx.y * 64, n0 = blockIdx.x * 64;
    __shared__ f16 tile[64][72];
    int t = threadIdx.x;
    #pragma unroll
    for (int i = 0; i < 4; i++) {
        int idx = t + i*256;
        int cr = idx >> 4, n4 = (idx & 15) * 4;
        float4 v = *(const float4*)(src + (size_t)(c0+cr)*NSP + n0 + n4);
        tile[cr][n4+0] = (f16)v.x; tile[cr][n4+1] = (f16)v.y;
        tile[cr][n4+2] = (f16)v.z; tile[cr][n4+3] = (f16)v.w;
    }
    __syncthreads();
    {
        int row = t >> 2, seg = (t & 3) * 16;
        float s1 = 0.f, s2 = 0.f;
        #pragma unroll
        for (int j = 0; j < 16; j++) {
            float x = (float)tile[row][seg + j];
            s1 += x; s2 += x * x;
        }
        s1 += __shfl_down(s1, 2, 4); s1 += __shfl_down(s1, 1, 4);
        s2 += __shfl_down(s2, 2, 4); s2 += __shfl_down(s2, 1, 4);
        if ((t & 3) == 0) {
            int si = is_style * 2 * NB * CH + b * CH + c0 + row;
            atomicAdd(&raw[si], s1);
            atomicAdd(&raw[si + NB * CH], s2);
        }
    }
    int nr = t >> 2, seg = (t & 3) * 16;
    __align__(16) f16 out_v[16];
    #pragma unroll
    for (int j = 0; j < 16; j++) out_v[j] = tile[seg + j][nr];
    f16* dp = dst + (size_t)(n0+nr)*CH + c0 + seg;
    *(int4*)dp = ((int4*)out_v)[0];
    *(int4*)(dp + 8) = ((int4*)out_v)[1];
}

// ---------------------------------------------------------------- effective weights (from raw sums)
__global__ void effw_kernel(const float* __restrict__ fw, const float* __restrict__ fb,
                            const float* __restrict__ gw, const float* __restrict__ gb,
                            const float* __restrict__ hw, const float* __restrict__ ow,
                            const float* __restrict__ raw,
                            f16* __restrict__ fw_e, float* __restrict__ fb_e,
                            f16* __restrict__ gw_e, float* __restrict__ gb_e,
                            f16* __restrict__ hw_h, f16* __restrict__ ow_h)
{
    int o = blockIdx.x, b = blockIdx.y, mode = blockIdx.z, t = threadIdx.x;
    if (mode >= 2) {
        if (b != 0) return;
        const float* srcw = (mode == 2) ? hw : ow;
        f16* dstw = (mode == 2) ? hw_h : ow_h;
        for (int c = t; c < CH; c += 128) dstw[o*CH + c] = (f16)srcw[o*CH + c];
        return;
    }
    const float* w  = mode ? gw : fw;
    const float* rw = raw + (mode ? 2*NB*CH : 0);
    f16* we = mode ? gw_e : fw_e;
    float part = 0.f;
    for (int c = t; c < CH; c += 128) {
        float s1 = rw[b*CH + c], s2 = rw[NB*CH + b*CH + c];
        float mn = s1 * (1.f/NSP);
        float var = (s2 - (float)NSP*mn*mn) * (1.f/(NSP-1));
        float is = rsqrtf(var + 1e-5f);
        float wv = w[o*CH + c];
        we[((size_t)b*CH + o)*CH + c] = (f16)(wv * is);
        part += wv * mn * is;
    }
    #pragma unroll
    for (int off = 32; off; off >>= 1) part += __shfl_down(part, off);
    __shared__ float rr[2];
    if ((t & 63) == 0) rr[t >> 6] = part;
    __syncthreads();
    if (t == 0) (mode ? gb_e : fb_e)[b*CH + o] = (mode ? gb : fb)[o] - (rr[0] + rr[1]);
}

// ---------------------------------------------------------------- fused F/G/H conv GEMM (K=512), m97-style
__global__ __launch_bounds__(256)
void conv3_kernel(const f16* __restrict__ fw_e, const float* __restrict__ fb_e,
                  const f16* __restrict__ gw_e, const float* __restrict__ gb_e,
                  const f16* __restrict__ hw_h, const float* __restrict__ h_b,
                  const f16* __restrict__ content_t, const f16* __restrict__ style_t,
                  f16* __restrict__ F_t, f16* __restrict__ G_t, f16* __restrict__ H_)
{
    const int T = gridDim.x;   // 1536
    const int bid = blockIdx.x;
    const int tile = (bid & 7) * (T >> 3) + (bid >> 3);
    const int zz = tile >> 7, rem = tile & 127;
    const int mt = rem >> 5, nt = rem & 31;
    const int kind = zz >> 2, b = zz & 3;

    const f16* W; const float* bias; const f16* Xt; f16* Y;
    if (kind == 0)      { W = fw_e + (size_t)b*CH*CH; bias = fb_e + b*CH; Xt = content_t + (size_t)b*NSP*CH; Y = F_t + (size_t)b*NSP*CH; }
    else if (kind == 1) { W = gw_e + (size_t)b*CH*CH; bias = gb_e + b*CH; Xt = style_t + (size_t)b*NSP*CH; Y = G_t + (size_t)b*NSP*CH; }
    else                { W = hw_h;                    bias = h_b;         Xt = style_t + (size_t)b*NSP*CH; Y = H_ + (size_t)b*CH*NSP; }

    const int m0 = mt * 128, n0 = nt * 128;
    const int t = threadIdx.x, wave = t >> 6, lane = t & 63;
    const int l15 = lane & 15, l4 = lane >> 4;
    const int wm = (wave >> 1) * 64, wn = (wave & 1) * 64;

    __shared__ __align__(16) f16 Al[8192];
    __shared__ __align__(16) f16 Bl[8192];

    f32x4 acc[4][4] = {};

    for (int ks = 0; ks < CH/64; ks++) {
        const int kk = ks * 64;
        #pragma unroll
        for (int j = 0; j < 4; j++) {
            int L  = ((wave*4 + j)*64 + lane) * 16;
            int SL = L ^ (((L >> 7) & 7) << 4);
            int row = SL >> 7, seg = (SL & 127) >> 1;
            gload_lds16(W  + (size_t)(m0 + row)*CH + kk + seg, &Al[L >> 1]);
            gload_lds16(Xt + (size_t)(n0 + row)*CH + kk + seg, &Bl[L >> 1]);
        }
        VM0; BARS;
        #pragma unroll
        for (int kb = 0; kb < 2; kb++) {
            half8 a[4], bb[4];
            #pragma unroll
            for (int i = 0; i < 4; i++) {
                int ab = (wm + i*16 + l15)*128 + kb*64 + l4*16;
                ab ^= ((ab >> 7) & 7) << 4;
                a[i] = *(const half8*)&Al[ab >> 1];
                int bby = (wn + i*16 + l15)*128 + kb*64 + l4*16;
                bby ^= ((bby >> 7) & 7) << 4;
                bb[i] = *(const half8*)&Bl[bby >> 1];
            }
            #pragma unroll
            for (int i = 0; i < 4; i++)
                #pragma unroll
                for (int jj = 0; jj < 4; jj++)
                    acc[i][jj] = __builtin_amdgcn_mfma_f32_16x16x32_f16(a[i], bb[jj], acc[i][jj], 0, 0, 0);
        }
        BARS;
    }

    #pragma unroll
    for (int i = 0; i < 4; i++) {
        const int ob = m0 + wm + i*16 + l4*4;
        f32x4 bv = *(const f32x4*)(bias + ob);
        #pragma unroll
        for (int jj = 0; jj < 4; jj++) {
            const int n = n0 + wn + jj*16 + l15;
            f32x4 v = acc[i][jj];
            v[0] += bv[0]; v[1] += bv[1]; v[2] += bv[2]; v[3] += bv[3];
            if (kind < 2) {
                half4 pk; pk[0]=(f16)v[0]; pk[1]=(f16)v[1]; pk[2]=(f16)v[2]; pk[3]=(f16)v[3];
                *(half4*)(Y + (size_t)n * CH + ob) = pk;
            } else {
                #pragma unroll
                for (int r = 0; r < 4; r++) Y[(size_t)(ob + r) * NSP + n] = (f16)v[r];
            }
        }
    }
}

// ---------------------------------------------------------------- 128x128 GEMM (out conv, fallback), proven R3
template<int MODE>   // 2: f32 Y[ob][n]
__global__ __launch_bounds__(256)
void gemm_kernel(const f16* __restrict__ W, long wstrideb,
                 const f16* __restrict__ Xt, long xstrideb,
                 const float* __restrict__ bias, long bstrideb,
                 void* __restrict__ Y, long ystrideb,
                 int K, long ostride)
{
    const int z = blockIdx.z;
    W    += (size_t)z * wstrideb;
    Xt   += (size_t)z * xstrideb;
    bias += (size_t)z * bstrideb;
    const int m0 = blockIdx.y * 128, n0 = blockIdx.x * 128;
    const int t = threadIdx.x, wave = t >> 6, lane = t & 63;
    const int l15 = lane & 15, l4 = lane >> 4;
    const int wm = (wave >> 1) * 64, wn = (wave & 1) * 64;

    __shared__ __align__(16) f16 Al[2][8192];
    __shared__ __align__(16) f16 Bl[2][8192];

    f32x4 acc[4][4] = {};

    auto stage = [&](int bufi, int kk) {
        #pragma unroll
        for (int j = 0; j < 4; j++) {
            int L  = ((wave*4 + j)*64 + lane) * 16;
            int SL = L ^ (((L >> 7) & 7) << 4);
            int row = SL >> 7, seg = (SL & 127) >> 1;
            gload_lds16(W  + (size_t)(m0 + row)*K + kk + seg, &Al[bufi][L >> 1]);
            gload_lds16(Xt + (size_t)(n0 + row)*K + kk + seg, &Bl[bufi][L >> 1]);
        }
    };

    const int nks = K >> 6;
    stage(0, 0);
    for (int ks = 0; ks < nks; ks++) {
        int bufi = ks & 1;
        if (ks < nks-1) { stage(bufi ^ 1, (ks + 1) * 64); VM8; }
        else            { VM0; }
        BARS;
        #pragma unroll
        for (int kb = 0; kb < 2; kb++) {
            half8 a[4], bb[4];
            #pragma unroll
            for (int i = 0; i < 4; i++) {
                int ab = (wm + i*16 + l15)*128 + kb*64 + l4*16;
                ab ^= ((ab >> 7) & 7) << 4;
                a[i] = *(const half8*)&Al[bufi][ab >> 1];
                int bby = (wn + i*16 + l15)*128 + kb*64 + l4*16;
                bby ^= ((bby >> 7) & 7) << 4;
                bb[i] = *(const half8*)&Bl[bufi][bby >> 1];
            }
            #pragma unroll
            for (int i = 0; i < 4; i++)
                #pragma unroll
                for (int jj = 0; jj < 4; jj++)
                    acc[i][jj] = __builtin_amdgcn_mfma_f32_16x16x32_f16(a[i], bb[jj], acc[i][jj], 0, 0, 0);
        }
        BARS;
    }

    #pragma unroll
    for (int i = 0; i < 4; i++) {
        const int ob = m0 + wm + i*16 + l4*4;
        f32x4 bv = *(const f32x4*)(bias + ob);
        #pragma unroll
        for (int jj = 0; jj < 4; jj++) {
            const int n = n0 + wn + jj*16 + l15;
            f32x4 v = acc[i][jj];
            v[0] += bv[0]; v[1] += bv[1]; v[2] += bv[2]; v[3] += bv[3];
            float* Yf = (float*)Y + (size_t)z * ystrideb;
            #pragma unroll
            for (int r = 0; r < 4; r++) Yf[(size_t)(ob + r) * ostride + n] = v[r];
        }
    }
}

// ---------------------------------------------------------------- fused out conv: Y[o][n] = sum_c ow[o][c]*(P0[n][c]+P1[n][c]) + o_b[o]
__global__ __launch_bounds__(256)
void out_fused_kernel(const f16* __restrict__ W, const f16* __restrict__ P0, const f16* __restrict__ P1,
                      const float* __restrict__ bias, float* __restrict__ Y)
{
    const int z = blockIdx.z;
    const f16* p0 = P0 + (size_t)z * NSP * CH;
    const f16* p1 = P1 + (size_t)z * NSP * CH;
    float* Yf = Y + (size_t)z * CH * NSP;
    const int m0 = blockIdx.y * 128, n0 = blockIdx.x * 128;
    const int t = threadIdx.x, wave = t >> 6, lane = t & 63;
    const int l15 = lane & 15, l4 = lane >> 4;
    const int wm = (wave >> 1) * 64, wn = (wave & 1) * 64;

    __shared__ __align__(16) f16 Al[8192];
    __shared__ __align__(16) f16 Bl[8192];

    f32x4 acc[4][4] = {};

    for (int ks = 0; ks < CH/64; ks++) {
        const int kk = ks * 64;
        int Ls[4];
        half8 b0[4], b1[4];
        #pragma unroll
        for (int j = 0; j < 4; j++) {
            int L  = ((wave*4 + j)*64 + lane) * 16;
            int SL = L ^ (((L >> 7) & 7) << 4);
            int row = SL >> 7, seg = (SL & 127) >> 1;
            gload_lds16(W + (size_t)(m0 + row)*CH + kk + seg, &Al[L >> 1]);
            b0[j] = *(const half8*)(p0 + (size_t)(n0 + row)*CH + kk + seg);
            b1[j] = *(const half8*)(p1 + (size_t)(n0 + row)*CH + kk + seg);
            Ls[j] = L;
        }
        #pragma unroll
        for (int j = 0; j < 4; j++) {
            half8 s;
            #pragma unroll
            for (int e = 0; e < 8; e++) s[e] = (f16)((float)b0[j][e] + (float)b1[j][e]);
            *(half8*)&Bl[Ls[j] >> 1] = s;
        }
        __syncthreads();    // drains vmcnt (gload_lds) + lgkm (ds_write)
        #pragma unroll
        for (int kb = 0; kb < 2; kb++) {
            half8 a[4], bb[4];
            #pragma unroll
            for (int i = 0; i < 4; i++) {
                int ab = (wm + i*16 + l15)*128 + kb*64 + l4*16;
                ab ^= ((ab >> 7) & 7) << 4;
                a[i] = *(const half8*)&Al[ab >> 1];
                int bby = (wn + i*16 + l15)*128 + kb*64 + l4*16;
                bby ^= ((bby >> 7) & 7) << 4;
                bb[i] = *(const half8*)&Bl[bby >> 1];
            }
            #pragma unroll
            for (int i = 0; i < 4; i++)
                #pragma unroll
                for (int jj = 0; jj < 4; jj++)
                    acc[i][jj] = __builtin_amdgcn_mfma_f32_16x16x32_f16(a[i], bb[jj], acc[i][jj], 0, 0, 0);
        }
        __syncthreads();
    }

    #pragma unroll
    for (int i = 0; i < 4; i++) {
        const int ob = m0 + wm + i*16 + l4*4;
        f32x4 bv = *(const f32x4*)(bias + ob);
        #pragma unroll
        for (int jj = 0; jj < 4; jj++) {
            const int n = n0 + wn + jj*16 + l15;
            f32x4 v = acc[i][jj];
            #pragma unroll
            for (int r = 0; r < 4; r++) Yf[(size_t)(ob + r) * NSP + n] = v[r] + bv[r];
        }
    }
}

// ---------------------------------------------------------------- attention GEMM fallback (m97-style)
template<int TPB, int NCT>
__global__ __launch_bounds__(256)
void gemm_att_kernel(const f16* __restrict__ W, long wstrideb,
                     const f16* __restrict__ Xt, long xstrideb,
                     f16* __restrict__ Y, long ystrideb,
                     int K, long ostride)
{
    const int T = gridDim.x;
    const int bid = blockIdx.x;
    const int tile = (bid & 7) * (T >> 3) + (bid >> 3);
    const int z = tile / TPB, rem = tile - z * TPB;
    const int mt = rem / NCT, nt = rem - mt * NCT;
    W  += (size_t)z * wstrideb;
    Xt += (size_t)z * xstrideb;
    f16* Yb = Y + (size_t)z * ystrideb;
    const int m0 = mt * 128, n0 = nt * 128;

    const int t = threadIdx.x, wave = t >> 6, lane = t & 63;
    const int l15 = lane & 15, l4 = lane >> 4;
    const int wm = (wave >> 1) * 64, wn = (wave & 1) * 64;

    __shared__ __align__(16) f16 Al[8192];
    __shared__ __align__(16) f16 Bl[8192];

    f32x4 acc[4][4] = {};

    const int nks = K >> 6;
    for (int ks = 0; ks < nks; ks++) {
        const int kk = ks * 64;
        #pragma unroll
        for (int j = 0; j < 4; j++) {
            int L  = ((wave*4 + j)*64 + lane) * 16;
            int SL = L ^ (((L >> 7) & 7) << 4);
            int row = SL >> 7, seg = (SL & 127) >> 1;
            gload_lds16(W  + (size_t)(m0 + row)*K + kk + seg, &Al[L >> 1]);
            gload_lds16(Xt + (size_t)(n0 + row)*K + kk + seg, &Bl[L >> 1]);
        }
        VM0; BARS;
        #pragma unroll
        for (int kb = 0; kb < 2; kb++) {
            half8 a[4], bb[4];
            #pragma unroll
            for (int i = 0; i < 4; i++) {
                int ab = (wm + i*16 + l15)*128 + kb*64 + l4*16;
                ab ^= ((ab >> 7) & 7) << 4;
                a[i] = *(const half8*)&Al[ab >> 1];
                int bby = (wn + i*16 + l15)*128 + kb*64 + l4*16;
                bby ^= ((bby >> 7) & 7) << 4;
                bb[i] = *(const half8*)&Bl[bby >> 1];
            }
            #pragma unroll
            for (int i = 0; i < 4; i++)
                #pragma unroll
                for (int jj = 0; jj < 4; jj++)
                    acc[i][jj] = __builtin_amdgcn_mfma_f32_16x16x32_f16(a[i], bb[jj], acc[i][jj], 0, 0, 0);
        }
        BARS;
    }

    #pragma unroll
    for (int i = 0; i < 4; i++) {
        const int ob = m0 + wm + i*16 + l4*4;
        #pragma unroll
        for (int jj = 0; jj < 4; jj++) {
            const int ncol = n0 + wn + jj*16 + l15;
            #pragma unroll
            for (int r = 0; r < 4; r++)
                Yb[(size_t)(ob + r) * ostride + ncol] = (f16)acc[i][jj][r];
        }
    }
}

// ---------------------------------------------------------------- 256x256 8-phase GEMM (m201-faithful, proven R10)
template<int TPB, int NCT, int SPLITK>
__global__ __launch_bounds__(512)
void gemm256_kernel(const f16* __restrict__ W, long wstrideb,
                    const f16* __restrict__ Xt, long xstrideb,
                    f16* __restrict__ Y0, f16* __restrict__ Y1, long ystrideb,
                    int K, int kstride, long ostride)
{
    const int T = gridDim.x;
    const int bid = blockIdx.x;
    const int tile = (bid & 7) * (T >> 3) + (bid >> 3);
    int rem = tile, sp = 0;
    if constexpr (SPLITK == 2) { sp = tile / (NB * TPB); rem = tile - sp * NB * TPB; }
    const int z = rem / TPB; rem -= z * TPB;
    const int mt = rem / NCT, nt = rem - mt * NCT;
    const f16* Wb = W  + (size_t)z * wstrideb + (size_t)sp * K;
    const f16* Xb = Xt + (size_t)z * xstrideb + (size_t)sp * K;
    f16* Yb = ((SPLITK == 2 && sp) ? Y1 : Y0) + (size_t)z * ystrideb;
    const int m0 = mt * 256, n0 = nt * 256;

    const int t = threadIdx.x, lane = t & 63, wave = t >> 6;
    const int l15 = lane & 15, l4 = lane >> 4;
    const int wr = wave >> 2, wc = wave & 3;

    __shared__ __align__(16) f16 As[2][16384];
    __shared__ __align__(16) f16 Bs[2][16384];

    f32x4 acc[8][4] = {};

    auto stA = [&](int nbuf, int kk, int half, int q) {
        int L  = half*16384 + q*8192 + t*16;
        int SL = L ^ (((L >> 7) & 7) << 4);
        gload_lds16(Wb + (size_t)(m0 + (SL >> 7)) * kstride + kk + ((SL & 127) >> 1), &As[nbuf][L >> 1]);
    };
    auto stB = [&](int nbuf, int kk, int half, int q) {
        int L  = half*16384 + q*8192 + t*16;
        int SL = L ^ (((L >> 7) & 7) << 4);
        gload_lds16(Xb + (size_t)(n0 + (SL >> 7)) * kstride + kk + ((SL & 127) >> 1), &Bs[nbuf][L >> 1]);
    };
    auto ldA = [&](int buf, int i, int kb) {
        int L = (((i&3)*16) + wr*64 + ((i>>2)*128) + l15)*128 + kb*64 + l4*16;
        L ^= ((L >> 7) & 7) << 4;
        return *(const half8*)&As[buf][L >> 1];
    };
    auto ldB = [&](int buf, int j, int kb) {
        int L = (((j&1)*16) + wc*32 + ((j>>1)*128) + l15)*128 + kb*64 + l4*16;
        L ^= ((L >> 7) & 7) << 4;
        return *(const half8*)&Bs[buf][L >> 1];
    };

    const int nks = K >> 6;
    stA(0,0,0,0); stA(0,0,0,1);
    stB(0,0,0,0); stB(0,0,0,1);
    stB(0,0,1,0); stB(0,0,1,1);
    stA(0,0,1,0); stA(0,0,1,1);
    VM4;
    if (nks > 1) {
        stA(1,64,0,0); stA(1,64,0,1);
        stB(1,64,0,0); stB(1,64,0,1);
        stB(1,64,1,0); stB(1,64,1,1);
        VM6;
    } else { VM0; }
    BARS;

    half8 a[4][2], b01[2][2], b23[2][2];

    for (int kt = 0; kt < nks; kt++) {
        const int buf = kt & 1;
        const int kk1 = (kt+1) << 6, kk2 = (kt+2) << 6;
        const bool s1 = (kt+1 < nks), s2 = (kt+2 < nks);

        // ---- p1: reads A0(i0-3)+B0(j0-1); stage t+1.A1 -> buf^1
        #pragma unroll
        for (int i = 0; i < 4; i++) { a[i][0] = ldA(buf, i, 0); a[i][1] = ldA(buf, i, 1); }
        #pragma unroll
        for (int j = 0; j < 2; j++) { b01[j][0] = ldB(buf, j, 0); b01[j][1] = ldB(buf, j, 1); }
        if (s1) { stA(buf^1, kk1, 1, 0); stA(buf^1, kk1, 1, 1); }
        else    { VM2; }
        BARS; SP1;
        #pragma unroll
        for (int i = 0; i < 4; i++)
            #pragma unroll
            for (int j = 0; j < 2; j++)
                #pragma unroll
                for (int kb = 0; kb < 2; kb++)
                    acc[i][j] = __builtin_amdgcn_mfma_f32_16x16x32_f16(a[i][kb], b01[j][kb], acc[i][j], 0, 0, 0);
        SP0; BARS;

        // ---- p2: reads B1(j2-3); stage t+2.A0 -> buf
        #pragma unroll
        for (int j = 0; j < 2; j++) { b23[j][0] = ldB(buf, 2+j, 0); b23[j][1] = ldB(buf, 2+j, 1); }
        if (s2)       { stA(buf, kk2, 0, 0); stA(buf, kk2, 0, 1); }
        else if (!s1) { VM0; }
        BARS; SP1;
        #pragma unroll
        for (int i = 0; i < 4; i++)
            #pragma unroll
            for (int j = 0; j < 2; j++)
                #pragma unroll
                for (int kb = 0; kb < 2; kb++)
                    acc[i][2+j] = __builtin_amdgcn_mfma_f32_16x16x32_f16(a[i][kb], b23[j][kb], acc[i][2+j], 0, 0, 0);
        SP0; BARS;

        // ---- p3: reads A1(i4-7); stage t+2.B0 -> buf
        #pragma unroll
        for (int i = 0; i < 4; i++) { a[i][0] = ldA(buf, 4+i, 0); a[i][1] = ldA(buf, 4+i, 1); }
        if (s2) { stB(buf, kk2, 0, 0); stB(buf, kk2, 0, 1); }
        BARS; SP1;
        #pragma unroll
        for (int i = 0; i < 4; i++)
            #pragma unroll
            for (int j = 0; j < 2; j++)
                #pragma unroll
                for (int kb = 0; kb < 2; kb++)
                    acc[4+i][2+j] = __builtin_amdgcn_mfma_f32_16x16x32_f16(a[i][kb], b23[j][kb], acc[4+i][2+j], 0, 0, 0);
        SP0; BARS;

        // ---- p4: no new reads; stage t+2.B1 -> buf; K-tile wait
        if (s2)      { stB(buf, kk2, 1, 0); stB(buf, kk2, 1, 1); VM6; }
        else if (s1) { VM4; }
        BARS; SP1;
        #pragma unroll
        for (int i = 0; i < 4; i++)
            #pragma unroll
            for (int j = 0; j < 2; j++)
                #pragma unroll
                for (int kb = 0; kb < 2; kb++)
                    acc[4+i][j] = __builtin_amdgcn_mfma_f32_16x16x32_f16(a[i][kb], b01[j][kb], acc[4+i][j], 0, 0, 0);
        SP0; BARS;
    }

    #pragma unroll
    for (int i = 0; i < 8; i++) {
        const int ob = m0 + ((i&3)*16) + wr*64 + ((i>>2)*128) + l4*4;
        #pragma unroll
        for (int j = 0; j < 4; j++) {
            const int ncol = n0 + ((j&1)*16) + wc*32 + ((j>>1)*128) + l15;
            f32x4 v = acc[i][j];
            #pragma unroll
            for (int r = 0; r < 4; r++)
                Yb[(size_t)(ob + r) * ostride + ncol] = (f16)v[r];
        }
    }
}

// ---------------------------------------------------------------- row softmax (in place, f16)
__global__ __launch_bounds__(256)
void softmax_kernel(f16* __restrict__ S, int nrows)
{
    int row = blockIdx.x * 4 + (threadIdx.x >> 6);
    if (row >= nrows) return;
    int lane = threadIdx.x & 63;
    f16* p = S + (size_t)row * NSP + lane * 8;

    half8 v[8];
    #pragma unroll
    for (int j = 0; j < 8; j++) v[j] = *(const half8*)(p + j * 512);

    float mx = -1e30f;
    #pragma unroll
    for (int j = 0; j < 8; j++)
        #pragma unroll
        for (int e = 0; e < 8; e++) mx = fmaxf(mx, (float)v[j][e]);
    #pragma unroll
    for (int off = 32; off; off >>= 1) mx = fmaxf(mx, __shfl_xor(mx, off));

    float ex[64];
    float s = 0.f;
    #pragma unroll
    for (int j = 0; j < 8; j++)
        #pragma unroll
        for (int e = 0; e < 8; e++) {
            float x = __expf((float)v[j][e] - mx);
            ex[j*8 + e] = x; s += x;
        }
    #pragma unroll
    for (int off = 32; off; off >>= 1) s += __shfl_xor(s, off);
    float inv = 1.0f / s;

    #pragma unroll
    for (int j = 0; j < 8; j++) {
        half8 o;
        #pragma unroll
        for (int e = 0; e < 8; e++) o[e] = (f16)(ex[j*8 + e] * inv);
        *(half8*)(p + j * 512) = o;
    }
}

// ---------------------------------------------------------------- launch
extern "C" void kernel_launch(void* const* d_in, const int* in_sizes, int n_in,
                              void* d_out, int out_size, void* d_ws, size_t ws_size,
                              hipStream_t stream)
{
    const float* content = (const float*)d_in[0];
    const float* style   = (const float*)d_in[1];
    const float* f_w = (const float*)d_in[2];
    const float* f_b = (const float*)d_in[3];
    const float* g_w = (const float*)d_in[4];
    const float* g_b = (const float*)d_in[5];
    const float* h_w = (const float*)d_in[6];
    const float* h_b = (const float*)d_in[7];
    const float* o_w = (const float*)d_in[8];
    const float* o_b = (const float*)d_in[9];

    char* ws = (char*)d_ws;
    size_t off = 0;
    auto alloc = [&](size_t bytes) -> void* {
        void* p = ws + off;
        off += (bytes + 255) & ~(size_t)255;
        return p;
    };
    float* raw = (float*)alloc(4 * NB*CH * 4);
    f16* fw_e = (f16*)alloc((size_t)NB*CH*CH*2);
    f16* gw_e = (f16*)alloc((size_t)NB*CH*CH*2);
    f16* hw_h = (f16*)alloc((size_t)CH*CH*2);
    f16* ow_h = (f16*)alloc((size_t)CH*CH*2);
    float* fb_e = (float*)alloc((size_t)NB*CH*4);
    float* gb_e = (float*)alloc((size_t)NB*CH*4);
    f16* content_t = (f16*)alloc((size_t)NB*NSP*CH*2);
    f16* style_t   = (f16*)alloc((size_t)NB*NSP*CH*2);
    f16* F_t = (f16*)alloc((size_t)NB*NSP*CH*2);
    f16* G_t = (f16*)alloc((size_t)NB*NSP*CH*2);
    f16* H_  = (f16*)alloc((size_t)NB*CH*NSP*2);
    f16* styled_t = content_t;           // fallback path only

    size_t s_plane = (size_t)NSP * NSP;
    bool all4 = (off + 4 * s_plane * 2 <= ws_size);
    f16* S16 = (f16*)alloc((all4 ? 4 : 1) * s_plane * 2);
    if (off > ws_size) return;

    hipMemsetAsync(raw, 0, 4 * NB*CH * 4, stream);
    transpose_f16_kernel<<<dim3(NSP/64, CH/64, NB*2), dim3(256), 0, stream>>>(
        content, style, content_t, style_t, raw);
    effw_kernel<<<dim3(CH, NB, 4), dim3(128), 0, stream>>>(f_w, f_b, g_w, g_b, h_w, o_w, raw,
                                                           fw_e, fb_e, gw_e, gb_e, hw_h, ow_h);
    conv3_kernel<<<dim3(12*128), dim3(256), 0, stream>>>(
        fw_e, fb_e, gw_e, gb_e, hw_h, h_b, content_t, style_t, F_t, G_t, H_);

    if (all4) {
        // S[n][m]: W=F_t (ob=n), Xt=G_t (ncol=m), MODE0 row store (R10 config); 16x16 tiles x 4 b
        gemm256_kernel<256,16,1><<<dim3(1024), dim3(512), 0, stream>>>(
            F_t, (long)NSP*CH, G_t, (long)NSP*CH, S16, nullptr, (long)s_plane, CH, CH, (long)NSP);
        softmax_kernel<<<dim3(NB*NSP/4), dim3(256), 0, stream>>>(S16, NB*NSP);
        // PV split-K=2 (proven R10): W=S16 (ob=n), Xt=H_ (ncol=c); partials into F_t/G_t
        gemm256_kernel<32,2,2><<<dim3(256), dim3(512), 0, stream>>>(
            S16, (long)s_plane, H_, (long)CH*NSP, F_t, G_t, (long)NSP*CH, NSP/2, NSP, (long)CH);
        // fused out conv: reads P0,P1 directly (f32 add), writes f32 d_out
        out_fused_kernel<<<dim3(NSP/128, CH/128, NB), dim3(256), 0, stream>>>(
            ow_h, F_t, G_t, o_b, (float*)d_out);
    } else {
        for (int b = 0; b < NB; b++) {
            gemm_att_kernel<1024,32><<<dim3(1024), dim3(256), 0, stream>>>(
                F_t + (size_t)b*NSP*CH, 0L, G_t + (size_t)b*NSP*CH, 0L,
                S16, 0L, CH, (long)NSP);
            softmax_kernel<<<dim3(NSP/4), dim3(256), 0, stream>>>(S16, NSP);
            gemm_att_kernel<128,4><<<dim3(128), dim3(256), 0, stream>>>(
                S16, 0L, H_ + (size_t)b*CH*NSP, 0L,
                styled_t + (size_t)b*NSP*CH, 0L, NSP, (long)CH);
        }
        gemm_kernel<2><<<dim3(NSP/128, CH/128, NB), dim3(256), 0, stream>>>(
            ow_h, 0L, styled_t, (long)NSP*CH, o_b, 0L, d_out, (long)CH*NSP, CH, (long)NSP);
    }
}